// Round 1
// baseline (4575.826 us; speedup 1.0000x reference)
//
#include <hip/hip_runtime.h>
#include <hip/hip_bf16.h>

#define HW 65536
#define WIDTH 256

// ---------------- Spatial window-attention branch ----------------
// one workgroup = one 8x8 window (8192 WGs), 256 threads
__global__ __launch_bounds__(256) void k_spatial(
    const float* __restrict__ x, const float* __restrict__ illu,
    const float* __restrict__ ln1w, const float* __restrict__ wqkv,
    const float* __restrict__ bqkv, const float* __restrict__ rpb,
    const float* __restrict__ wproj, const float* __restrict__ bproj,
    float* __restrict__ out)
{
  __shared__ float xw[64][65];   // token-major x window -> illu window -> attn out
  __shared__ float qs[64][65];
  __shared__ float ks[64][65];
  __shared__ float vs[64][65];
  __shared__ float wq[12288];    // staged w_qkv, later reused for w_proj
  __shared__ float rpbs[900];
  __shared__ float rs_tok[64];

  const int tid = threadIdx.x;
  const int blk = blockIdx.x;
  const int b = blk >> 10;
  const int win = blk & 1023;
  const int h0 = (win >> 5) << 3;
  const int w0 = (win & 31) << 3;
  const float* xb = x + (size_t)b * 64 * HW;

  for (int i = tid; i < 900; i += 256) rpbs[i] = rpb[i];
  for (int i = tid; i < 12288; i += 256) wq[i] = wqkv[i];
  for (int i = tid; i < 4096; i += 256) {
    int c = i >> 6, p = i & 63;
    xw[p][c] = xb[(size_t)c * HW + (h0 + (p >> 3)) * WIDTH + w0 + (p & 7)];
  }
  __syncthreads();
  // biasfree LN stats per token (var uses mean, output does not subtract mean)
  {
    int l = tid >> 2, q = tid & 3;
    float s = 0.f, s2 = 0.f;
    #pragma unroll
    for (int c = 0; c < 16; ++c) { float v = xw[l][q * 16 + c]; s += v; s2 += v * v; }
    s += __shfl_down(s, 1); s2 += __shfl_down(s2, 1);
    s += __shfl_down(s, 2); s2 += __shfl_down(s2, 2);
    if (q == 0) {
      float mean = s * 0.015625f;
      float var = s2 * 0.015625f - mean * mean;
      rs_tok[l] = rsqrtf(var + 1e-5f);
    }
  }
  __syncthreads();
  for (int i = tid; i < 4096; i += 256) {
    int l = i >> 6, c = i & 63;
    xw[l][c] *= rs_tok[l] * ln1w[c];
  }
  __syncthreads();
  // qkv GEMM: [64 tokens x 192 out], lane = token, 4-acc ILP over out chans
  {
    int l = tid & 63;
    int o0 = tid >> 6;  // 0..3 (wave-uniform)
    for (int kb = 0; kb < 12; ++kb) {
      int ob = o0 + kb * 16;
      float a0 = bqkv[ob], a1 = bqkv[ob + 4], a2 = bqkv[ob + 8], a3 = bqkv[ob + 12];
      #pragma unroll
      for (int c = 0; c < 64; ++c) {
        float xv = xw[l][c];
        const float* wr = &wq[c * 192 + ob];
        a0 += xv * wr[0];
        a1 += xv * wr[4];
        a2 += xv * wr[8];
        a3 += xv * wr[12];
      }
      if (kb < 4) {
        qs[l][ob] = a0 * 0.25f; qs[l][ob + 4] = a1 * 0.25f;
        qs[l][ob + 8] = a2 * 0.25f; qs[l][ob + 12] = a3 * 0.25f;
      } else if (kb < 8) {
        int oo = ob - 64;
        ks[l][oo] = a0; ks[l][oo + 4] = a1; ks[l][oo + 8] = a2; ks[l][oo + 12] = a3;
      } else {
        int oo = ob - 128;
        vs[l][oo] = a0; vs[l][oo + 4] = a1; vs[l][oo + 8] = a2; vs[l][oo + 12] = a3;
      }
    }
  }
  __syncthreads();
  // stage illu window into xw (reuse) and w_proj into wq (reuse)
  {
    const float* ib = illu + (size_t)b * 64 * HW;
    for (int i = tid; i < 4096; i += 256) {
      int c = i >> 6, p = i & 63;
      xw[p][c] = ib[(size_t)c * HW + (h0 + (p >> 3)) * WIDTH + w0 + (p & 7)];
    }
    for (int i = tid; i < 4096; i += 256) wq[i] = wproj[i];
  }
  __syncthreads();
  for (int i = tid; i < 4096; i += 256) {
    int l = i >> 6, c = i & 63;
    vs[l][c] *= xw[l][c];     // illumination modulation of V
  }
  __syncthreads();
  // attention: wave = head, lane = query token
  {
    int hd = tid >> 6;
    int l = tid & 63;
    int hb = hd * 16;
    float qrow[16];
    #pragma unroll
    for (int d = 0; d < 16; ++d) qrow[d] = qs[l][hb + d];
    float arow[64];
    int li = l >> 3, lj = l & 7;
    float mx = -1e30f;
    #pragma unroll
    for (int m = 0; m < 64; ++m) {
      float s = 0.f;
      #pragma unroll
      for (int d = 0; d < 16; ++d) s += qrow[d] * ks[m][hb + d];
      int ridx = (li - (m >> 3) + 7) * 15 + (lj - (m & 7) + 7);
      s += rpbs[ridx * 4 + hd];
      arow[m] = s;
      mx = fmaxf(mx, s);
    }
    float ssum = 0.f;
    #pragma unroll
    for (int m = 0; m < 64; ++m) { float e = __expf(arow[m] - mx); arow[m] = e; ssum += e; }
    float inv = 1.f / ssum;
    float acc[16];
    #pragma unroll
    for (int d = 0; d < 16; ++d) acc[d] = 0.f;
    #pragma unroll
    for (int m = 0; m < 64; ++m) {
      float a = arow[m];
      #pragma unroll
      for (int d = 0; d < 16; ++d) acc[d] += a * vs[m][hb + d];
    }
    #pragma unroll
    for (int d = 0; d < 16; ++d) xw[l][hb + d] = acc[d] * inv;
  }
  __syncthreads();
  // proj + residual; pixel-fast mapping for coalesced stores
  {
    int p = tid & 63;
    int o0 = tid >> 6;
    int hh = h0 + (p >> 3), ww = w0 + (p & 7);
    float* ob_ = out + (size_t)b * 64 * HW + hh * WIDTH + ww;
    const float* xr = xb + hh * WIDTH + ww;
    for (int kb = 0; kb < 4; ++kb) {
      int o = o0 + kb * 16;
      float a0 = bproj[o], a1 = bproj[o + 4], a2 = bproj[o + 8], a3 = bproj[o + 12];
      #pragma unroll
      for (int c = 0; c < 64; ++c) {
        float av = xw[p][c];
        const float* wr = &wq[c * 64 + o];
        a0 += av * wr[0];
        a1 += av * wr[4];
        a2 += av * wr[8];
        a3 += av * wr[12];
      }
      ob_[(size_t)o * HW]        = xr[(size_t)o * HW]        + a0;
      ob_[(size_t)(o + 4) * HW]  = xr[(size_t)(o + 4) * HW]  + a1;
      ob_[(size_t)(o + 8) * HW]  = xr[(size_t)(o + 8) * HW]  + a2;
      ob_[(size_t)(o + 12) * HW] = xr[(size_t)(o + 12) * HW] + a3;
    }
  }
}

// ---------------- Channel branch producer: LN2 + 1x1 + dw3x3 ----------------
// one workgroup = one 16x16 pixel tile (2048 WGs), 256 threads
__global__ __launch_bounds__(256) void k_chan_qkv(
    const float* __restrict__ x, const float* __restrict__ illu,
    const float* __restrict__ ln2w, const float* __restrict__ w1,
    const float* __restrict__ wdw,
    __hip_bfloat16* __restrict__ vm, float* __restrict__ Gp,
    float* __restrict__ Nqp, float* __restrict__ Nkp)
{
  __shared__ float xm[64][325];            // normalized x, 18x18 halo
  __shared__ float tb[16][324];            // 1x1 output chunk over halo
  __shared__ __hip_bfloat16 qt[64][264];   // q over tile (stride 264 vs bank conflicts)
  __shared__ __hip_bfloat16 kc[16][264];   // current k chunk
  __shared__ float rsp[324];

  const int tid = threadIdx.x;
  const int blk = blockIdx.x;
  const int b = blk >> 8;
  const int tile = blk & 255;
  const int ty0 = (tile >> 4) * 16, tx0 = (tile & 15) * 16;
  const float* xb = x + (size_t)b * 64 * HW;

  for (int i = tid; i < 64 * 324; i += 256) {
    int c = i / 324, p = i - c * 324;
    int hy = p / 18, hx = p - hy * 18;
    int gy = ty0 + hy - 1, gx = tx0 + hx - 1;
    float v = 0.f;
    if (gy >= 0 && gy < 256 && gx >= 0 && gx < 256)
      v = xb[(size_t)c * HW + gy * WIDTH + gx];
    xm[c][p] = v;
  }
  __syncthreads();
  for (int r = 0; r < 2; ++r) {
    int p = r * 256 + tid;
    if (p < 324) {
      float s = 0.f, s2 = 0.f;
      #pragma unroll
      for (int c = 0; c < 64; ++c) { float v = xm[c][p]; s += v; s2 += v * v; }
      float mean = s * 0.015625f;
      float var = s2 * 0.015625f - mean * mean;
      rsp[p] = rsqrtf(var + 1e-5f);
    }
  }
  __syncthreads();
  for (int i = tid; i < 64 * 324; i += 256) {
    int c = i / 324, p = i - c * 324;
    xm[c][p] *= rsp[p] * ln2w[c];
  }
  __syncthreads();

  const int py = tid >> 4, px = tid & 15;

  for (int chunk = 0; chunk < 12; ++chunk) {
    const int ob = chunk * 16;
    // 1x1 conv into tb: 16 out-channels x 324 halo pixels, scalar weight loads
    for (int r = 0; r < 2; ++r) {
      int p = r * 256 + tid;
      if (p < 324) {
        #pragma unroll
        for (int og = 0; og < 4; ++og) {
          int o0 = ob + og * 4;
          float a0 = 0.f, a1 = 0.f, a2 = 0.f, a3 = 0.f;
          #pragma unroll
          for (int c = 0; c < 64; ++c) {
            float xv = xm[c][p];
            a0 += w1[(o0 + 0) * 64 + c] * xv;
            a1 += w1[(o0 + 1) * 64 + c] * xv;
            a2 += w1[(o0 + 2) * 64 + c] * xv;
            a3 += w1[(o0 + 3) * 64 + c] * xv;
          }
          tb[og * 4 + 0][p] = a0; tb[og * 4 + 1][p] = a1;
          tb[og * 4 + 2][p] = a2; tb[og * 4 + 3][p] = a3;
        }
      }
    }
    __syncthreads();
    // depthwise 3x3 at this thread's tile pixel for all 16 chunk channels
    float dout[16];
    #pragma unroll
    for (int oc = 0; oc < 16; ++oc) {
      const float* w9 = wdw + (size_t)(ob + oc) * 9;
      float a = 0.f;
      #pragma unroll
      for (int ky = 0; ky < 3; ++ky)
        #pragma unroll
        for (int kx = 0; kx < 3; ++kx)
          a += w9[ky * 3 + kx] * tb[oc][(py + ky) * 18 + px + kx];
      dout[oc] = a;
    }
    if (chunk < 4) {                      // q channels: keep in LDS
      #pragma unroll
      for (int oc = 0; oc < 16; ++oc)
        qt[ob + oc][tid] = __float2bfloat16(dout[oc]);
      __syncthreads();
    } else if (chunk < 8) {               // k channels: Gram + norm partials
      const int n = chunk - 4;            // head index
      #pragma unroll
      for (int oc = 0; oc < 16; ++oc)
        kc[oc][tid] = __float2bfloat16(dout[oc]);
      __syncthreads();
      int d = tid >> 4, e = tid & 15;
      float g = 0.f;
      for (int p = 0; p < 256; ++p)
        g += __bfloat162float(qt[n * 16 + d][p]) * __bfloat162float(kc[e][p]);
      Gp[((size_t)blk * 4 + n) * 256 + tid] = g;
      {
        int ch = tid >> 4, sg = tid & 15;
        float s = 0.f;
        for (int p = sg * 16; p < sg * 16 + 16; ++p) {
          float v = __bfloat162float(kc[ch][p]); s += v * v;
        }
        #pragma unroll
        for (int off = 1; off < 16; off <<= 1) s += __shfl_xor(s, off);
        if (sg == 0) Nkp[(size_t)blk * 64 + n * 16 + ch] = s;
      }
      __syncthreads();
    } else {                              // v channels: modulate by illu, store
      const int vb0 = (chunk - 8) * 16;
      const float* ib = illu + (size_t)b * 64 * HW;
      const int gy = ty0 + py, gx = tx0 + px;
      #pragma unroll
      for (int oc = 0; oc < 16; ++oc) {
        float iv = ib[(size_t)(vb0 + oc) * HW + gy * WIDTH + gx];
        vm[((size_t)b * 64 + vb0 + oc) * HW + gy * WIDTH + gx] =
            __float2bfloat16(dout[oc] * iv);
      }
      __syncthreads();
    }
  }
  // Nq partials (qt complete and intact)
  {
    int ch = tid >> 2, sg = tid & 3;
    float s = 0.f;
    for (int p = sg * 64; p < sg * 64 + 64; ++p) {
      float v = __bfloat162float(qt[ch][p]); s += v * v;
    }
    s += __shfl_down(s, 1);
    s += __shfl_down(s, 2);
    if (sg == 0) Nqp[(size_t)blk * 64 + ch] = s;
  }
}

// ---------------- reduce partials -> softmax -> fold w_out into M ----------------
__global__ __launch_bounds__(256) void k_reduce(
    const float* __restrict__ Gp, const float* __restrict__ Nqp,
    const float* __restrict__ Nkp, const float* __restrict__ temp,
    const float* __restrict__ wout, float* __restrict__ M)
{
  __shared__ float Gs[4][16][16];
  __shared__ float As[4][16][17];
  __shared__ float nq[64], nk[64];
  const int b = blockIdx.x;
  const int tid = threadIdx.x;

  float ga[4] = {0.f, 0.f, 0.f, 0.f};
  for (int t = 0; t < 256; ++t) {
    const float* g = Gp + (size_t)(b * 256 + t) * 1024;
    #pragma unroll
    for (int j = 0; j < 4; ++j) ga[j] += g[tid + j * 256];
  }
  #pragma unroll
  for (int j = 0; j < 4; ++j) {
    int o = tid + j * 256;
    Gs[o >> 8][(o >> 4) & 15][o & 15] = ga[j];
  }
  if (tid < 64) {
    float a = 0.f, k2 = 0.f;
    for (int t = 0; t < 256; ++t) {
      a  += Nqp[(size_t)(b * 256 + t) * 64 + tid];
      k2 += Nkp[(size_t)(b * 256 + t) * 64 + tid];
    }
    nq[tid] = fmaxf(sqrtf(a), 1e-12f);
    nk[tid] = fmaxf(sqrtf(k2), 1e-12f);
  }
  __syncthreads();
  if (tid < 64) {
    int n = tid >> 4, d = tid & 15;
    float tv = temp[n];
    float row[16];
    float mx = -1e30f;
    #pragma unroll
    for (int e = 0; e < 16; ++e) {
      float v = Gs[n][d][e] / (nq[n * 16 + d] * nk[n * 16 + e]) * tv;
      row[e] = v; mx = fmaxf(mx, v);
    }
    float s = 0.f;
    #pragma unroll
    for (int e = 0; e < 16; ++e) { float ev = __expf(row[e] - mx); row[e] = ev; s += ev; }
    float inv = 1.f / s;
    #pragma unroll
    for (int e = 0; e < 16; ++e) As[n][d][e] = row[e] * inv;
  }
  __syncthreads();
  float* Mb = M + (size_t)b * 4096;
  for (int i = tid; i < 4096; i += 256) {
    int o = i >> 6, cp = i & 63;
    int n = cp >> 4, e = cp & 15;
    float a = 0.f;
    #pragma unroll
    for (int d = 0; d < 16; ++d) a += wout[o * 64 + n * 16 + d] * As[n][d][e];
    Mb[i] = a;
  }
}

// ---------------- apply M to vm, accumulate into out ----------------
__global__ __launch_bounds__(256) void k_mdta_out(
    const __hip_bfloat16* __restrict__ vm, const float* __restrict__ M,
    float* __restrict__ out)
{
  __shared__ float vml[64][65];
  __shared__ float Ml[64][64];
  const int blk = blockIdx.x;
  const int b = blk >> 10;
  const int pix0 = (blk & 1023) << 6;
  const int tid = threadIdx.x;

  const float* Mb = M + (size_t)b * 4096;
  for (int i = tid; i < 4096; i += 256) Ml[i >> 6][i & 63] = Mb[i];
  const __hip_bfloat16* vb = vm + (size_t)b * 64 * HW;
  for (int i = tid; i < 4096; i += 256) {
    int c = i >> 6, p = i & 63;
    vml[c][p] = __bfloat162float(vb[(size_t)c * HW + pix0 + p]);
  }
  __syncthreads();
  float* ob = out + (size_t)b * 64 * HW;
  for (int i = tid; i < 4096; i += 256) {
    int o = i >> 6, p = i & 63;
    float acc = 0.f;
    #pragma unroll
    for (int c = 0; c < 64; ++c) acc += Ml[o][c] * vml[c][p];
    ob[(size_t)o * HW + pix0 + p] += acc;
  }
}

extern "C" void kernel_launch(void* const* d_in, const int* in_sizes, int n_in,
                              void* d_out, int out_size, void* d_ws, size_t ws_size,
                              hipStream_t stream) {
  const float* x     = (const float*)d_in[0];
  const float* illu  = (const float*)d_in[1];
  const float* ln1w  = (const float*)d_in[2];
  const float* ln2w  = (const float*)d_in[3];
  const float* wqkv  = (const float*)d_in[4];
  const float* bqkv  = (const float*)d_in[5];
  const float* rpb   = (const float*)d_in[6];
  const float* wproj = (const float*)d_in[7];
  const float* bproj = (const float*)d_in[8];
  const float* temp  = (const float*)d_in[9];
  const float* w1    = (const float*)d_in[10];
  const float* wdw   = (const float*)d_in[11];
  const float* wout  = (const float*)d_in[12];
  float* out = (float*)d_out;

  char* ws = (char*)d_ws;
  __hip_bfloat16* vm = (__hip_bfloat16*)ws;            // 8*64*65536*2  = 67108864 B
  float* Gp  = (float*)(ws + 67108864);                // 2048*1024*4   =  8388608 B
  float* Nqp = (float*)(ws + 75497472);                // 2048*64*4     =   524288 B
  float* Nkp = (float*)(ws + 76021760);                // 2048*64*4     =   524288 B
  float* M   = (float*)(ws + 76546048);                // 8*64*64*4     =   131072 B

  k_spatial<<<8192, 256, 0, stream>>>(x, illu, ln1w, wqkv, bqkv, rpb, wproj, bproj, out);
  k_chan_qkv<<<2048, 256, 0, stream>>>(x, illu, ln2w, w1, wdw, vm, Gp, Nqp, Nkp);
  k_reduce<<<8, 256, 0, stream>>>(Gp, Nqp, Nkp, temp, wout, M);
  k_mdta_out<<<8192, 256, 0, stream>>>(vm, M, out);
}

// Round 3
// 1579.026 us; speedup vs baseline: 2.8979x; 2.8979x over previous
//
#include <hip/hip_runtime.h>
#include <hip/hip_bf16.h>

#define HW 65536
#define WIDTH 256

typedef __attribute__((ext_vector_type(8))) short short8v;
typedef __attribute__((ext_vector_type(4))) short short4v;
typedef __attribute__((ext_vector_type(4))) float f32x4;

__device__ inline float bf2f(unsigned short u) {
  unsigned int i = ((unsigned int)u) << 16;
  float f; __builtin_memcpy(&f, &i, 4); return f;
}
__device__ inline unsigned short f2bf(float x) {
  __hip_bfloat16 h = __float2bfloat16(x);
  unsigned short u; __builtin_memcpy(&u, &h, 2); return u;
}

// swizzled LDS indexers (granule = 8 bf16 = 16B)
#define XH_IDX(p, g) ((p)*64 + ((((g) ^ ((p)&7)))<<3))            // halo: row p (0..335), granule g (0..7)
#define QC_IDX(ch, px) ((ch)*256 + ((((px)>>3) ^ ((ch)&7))<<3) + ((px)&7))  // q/k: row ch (0..15), px (0..255)
#define QCG_IDX(ch, G) ((ch)*256 + ((((G) ^ ((ch)&7)))<<3))       // granule G (0..31)

// ---------------- Spatial window-attention branch ----------------
// one workgroup = one 8x8 window (8192 WGs), 256 threads, bf16 tiles, 2 blocks/CU
__global__ __launch_bounds__(256, 2) void k_spatial(
    const float* __restrict__ x, const float* __restrict__ illu,
    const float* __restrict__ ln1w, const float* __restrict__ wqkv,
    const float* __restrict__ bqkv, const float* __restrict__ rpb,
    const float* __restrict__ wproj, const float* __restrict__ bproj,
    float* __restrict__ out)
{
  __shared__ __align__(16) unsigned short xw[64*72];   // raw x window -> illu -> (unused)
  __shared__ __align__(16) unsigned short qs[64*72];   // q (scaled) -> attn out
  __shared__ __align__(16) unsigned short ks[64*72];
  __shared__ __align__(16) unsigned short vs[64*72];
  __shared__ __align__(16) unsigned short wq[12288];   // w_qkv*ln1w bf16 -> wproj bf16
  __shared__ float rpbs[900];
  __shared__ float rs_tok[64];

  const int tid = threadIdx.x;
  const int blk = blockIdx.x;
  const int b = blk >> 10;
  const int win = blk & 1023;
  const int h0 = (win >> 5) << 3;
  const int w0 = (win & 31) << 3;
  const float* xb = x + (size_t)b * 64 * HW;

  for (int i = tid; i < 900; i += 256) rpbs[i] = rpb[i];
  for (int i = tid; i < 12288; i += 256) {
    int c = i / 192;
    wq[i] = f2bf(wqkv[i] * ln1w[c]);
  }
  for (int i = tid; i < 4096; i += 256) {
    int c = i >> 6, p = i & 63;
    xw[p*72 + c] = f2bf(xb[(size_t)c * HW + (h0 + (p >> 3)) * WIDTH + w0 + (p & 7)]);
  }
  __syncthreads();
  // LN stats per token from raw bf16 (fold rsqrt into qkv epilogue)
  {
    int l = tid >> 2, q4 = tid & 3;
    float s = 0.f, s2 = 0.f;
    #pragma unroll
    for (int c = 0; c < 16; ++c) {
      float v = bf2f(xw[l*72 + q4*16 + c]); s += v; s2 += v * v;
    }
    s += __shfl_down(s, 1); s2 += __shfl_down(s2, 1);
    s += __shfl_down(s, 2); s2 += __shfl_down(s2, 2);
    if (q4 == 0) {
      float mean = s * 0.015625f;
      float var = s2 * 0.015625f - mean * mean;
      rs_tok[l] = rsqrtf(var + 1e-5f);
    }
  }
  __syncthreads();
  // qkv GEMM: lane = token, thread owns 4 contiguous out-ch per chunk
  {
    int l = tid & 63, og = tid >> 6;
    float rs = rs_tok[l];
    for (int chunk = 0; chunk < 12; ++chunk) {
      int ob = chunk * 16 + og * 4;
      float a0 = 0.f, a1 = 0.f, a2 = 0.f, a3 = 0.f;
      #pragma unroll
      for (int c8 = 0; c8 < 8; ++c8) {
        short8v xv = *(const short8v*)&xw[l*72 + c8*8];
        #pragma unroll
        for (int j = 0; j < 8; ++j) {
          float xf = bf2f((unsigned short)xv[j]);
          short4v wv = *(const short4v*)&wq[(c8*8 + j)*192 + ob];
          a0 += xf * bf2f((unsigned short)wv[0]);
          a1 += xf * bf2f((unsigned short)wv[1]);
          a2 += xf * bf2f((unsigned short)wv[2]);
          a3 += xf * bf2f((unsigned short)wv[3]);
        }
      }
      float v0 = a0 * rs + bqkv[ob];
      float v1 = a1 * rs + bqkv[ob + 1];
      float v2 = a2 * rs + bqkv[ob + 2];
      float v3 = a3 * rs + bqkv[ob + 3];
      if (chunk < 4) {
        qs[l*72 + ob]     = f2bf(v0 * 0.25f); qs[l*72 + ob + 1] = f2bf(v1 * 0.25f);
        qs[l*72 + ob + 2] = f2bf(v2 * 0.25f); qs[l*72 + ob + 3] = f2bf(v3 * 0.25f);
      } else if (chunk < 8) {
        int oo = ob - 64;
        ks[l*72 + oo] = f2bf(v0); ks[l*72 + oo + 1] = f2bf(v1);
        ks[l*72 + oo + 2] = f2bf(v2); ks[l*72 + oo + 3] = f2bf(v3);
      } else {
        int oo = ob - 128;
        vs[l*72 + oo] = f2bf(v0); vs[l*72 + oo + 1] = f2bf(v1);
        vs[l*72 + oo + 2] = f2bf(v2); vs[l*72 + oo + 3] = f2bf(v3);
      }
    }
  }
  __syncthreads();
  // stage illu -> xw (overwrite) and wproj -> wq (overwrite)
  {
    const float* ib = illu + (size_t)b * 64 * HW;
    for (int i = tid; i < 4096; i += 256) {
      int c = i >> 6, p = i & 63;
      xw[p*72 + c] = f2bf(ib[(size_t)c * HW + (h0 + (p >> 3)) * WIDTH + w0 + (p & 7)]);
    }
    for (int i = tid; i < 4096; i += 256) wq[i] = f2bf(wproj[i]);
  }
  __syncthreads();
  for (int i = tid; i < 4096; i += 256) {
    int l = i >> 6, c = i & 63;
    vs[l*72 + c] = f2bf(bf2f(vs[l*72 + c]) * bf2f(xw[l*72 + c]));
  }
  __syncthreads();
  // attention: wave = head, lane = query token
  {
    int hd = tid >> 6;
    int l = tid & 63;
    int hb = hd * 16;
    float qrow[16];
    {
      short8v q0 = *(const short8v*)&qs[l*72 + hb];
      short8v q1 = *(const short8v*)&qs[l*72 + hb + 8];
      #pragma unroll
      for (int d = 0; d < 8; ++d) { qrow[d] = bf2f((unsigned short)q0[d]); qrow[d+8] = bf2f((unsigned short)q1[d]); }
    }
    float arow[64];
    int li = l >> 3, lj = l & 7;
    float mx = -1e30f;
    #pragma unroll 4
    for (int m = 0; m < 64; ++m) {
      short8v k0 = *(const short8v*)&ks[m*72 + hb];
      short8v k1 = *(const short8v*)&ks[m*72 + hb + 8];
      float s = 0.f;
      #pragma unroll
      for (int d = 0; d < 8; ++d) s += qrow[d] * bf2f((unsigned short)k0[d]) + qrow[d+8] * bf2f((unsigned short)k1[d]);
      int ridx = (li - (m >> 3) + 7) * 15 + (lj - (m & 7) + 7);
      s += rpbs[ridx * 4 + hd];
      arow[m] = s;
      mx = fmaxf(mx, s);
    }
    float ssum = 0.f;
    #pragma unroll
    for (int m = 0; m < 64; ++m) { float e = __expf(arow[m] - mx); arow[m] = e; ssum += e; }
    float inv = 1.f / ssum;
    float acc[16];
    #pragma unroll
    for (int d = 0; d < 16; ++d) acc[d] = 0.f;
    #pragma unroll 4
    for (int m = 0; m < 64; ++m) {
      short8v v0 = *(const short8v*)&vs[m*72 + hb];
      short8v v1 = *(const short8v*)&vs[m*72 + hb + 8];
      float a = arow[m];
      #pragma unroll
      for (int d = 0; d < 8; ++d) { acc[d] += a * bf2f((unsigned short)v0[d]); acc[d+8] += a * bf2f((unsigned short)v1[d]); }
    }
    #pragma unroll
    for (int d = 0; d < 16; ++d) qs[l*72 + hb + d] = f2bf(acc[d] * inv);  // wave-local cols
  }
  __syncthreads();
  // proj + bias + residual
  {
    int p = tid & 63, og = tid >> 6;
    int hh = h0 + (p >> 3), ww = w0 + (p & 7);
    float* op = out + (size_t)b * 64 * HW + hh * WIDTH + ww;
    const float* xr = xb + hh * WIDTH + ww;
    for (int chunk = 0; chunk < 4; ++chunk) {
      int o = chunk * 16 + og * 4;
      float a0 = 0.f, a1 = 0.f, a2 = 0.f, a3 = 0.f;
      #pragma unroll
      for (int c8 = 0; c8 < 8; ++c8) {
        short8v xv = *(const short8v*)&qs[p*72 + c8*8];
        #pragma unroll
        for (int j = 0; j < 8; ++j) {
          float xf = bf2f((unsigned short)xv[j]);
          short4v wv = *(const short4v*)&wq[(c8*8 + j)*64 + o];
          a0 += xf * bf2f((unsigned short)wv[0]);
          a1 += xf * bf2f((unsigned short)wv[1]);
          a2 += xf * bf2f((unsigned short)wv[2]);
          a3 += xf * bf2f((unsigned short)wv[3]);
        }
      }
      op[(size_t)o * HW]       = xr[(size_t)o * HW]       + a0 + bproj[o];
      op[(size_t)(o+1) * HW]   = xr[(size_t)(o+1) * HW]   + a1 + bproj[o+1];
      op[(size_t)(o+2) * HW]   = xr[(size_t)(o+2) * HW]   + a2 + bproj[o+2];
      op[(size_t)(o+3) * HW]   = xr[(size_t)(o+3) * HW]   + a3 + bproj[o+3];
    }
  }
}

// ---------------- Channel branch producer: LN2 + 1x1 (MFMA) + dw3x3 + Gram (MFMA) ----------------
// one workgroup = one 16x16 tile (2048 WGs), 256 threads, 75KB LDS, 2 blocks/CU
__global__ __launch_bounds__(256, 2) void k_chan_qkv(
    const float* __restrict__ x, const float* __restrict__ illu,
    const float* __restrict__ ln2w, const float* __restrict__ w1,
    const float* __restrict__ wdw,
    unsigned short* __restrict__ vm, float* __restrict__ Gp,
    float* __restrict__ Nqp, float* __restrict__ Nkp)
{
  __shared__ __align__(16) unsigned short xh[336*64];  // raw x halo, bf16, XOR-swizzled; rows 324..335 zero
  __shared__ __align__(16) unsigned short tb[16*344];  // 1x1 output chunk over halo (bf16)
  __shared__ __align__(16) unsigned short qc[16*256];  // q head chunk, swizzled
  __shared__ __align__(16) unsigned short kc[16*256];  // k head chunk, swizzled
  __shared__ float rsp[324];
  __shared__ unsigned short wdws[1728];                // dw weights bf16

  const int tid = threadIdx.x;
  const int blk = blockIdx.x;
  const int b = blk >> 8;
  const int tile = blk & 255;
  const int ty0 = (tile >> 4) << 4, tx0 = (tile & 15) << 4;
  const float* xb = x + (size_t)b * 64 * HW;

  for (int i = tid; i < 64 * 324; i += 256) {
    int c = i / 324, p = i - c * 324;
    int hy = p / 18, hx = p - hy * 18;
    int gy = ty0 + hy - 1, gx = tx0 + hx - 1;
    float v = 0.f;
    if (gy >= 0 && gy < 256 && gx >= 0 && gx < 256)
      v = xb[(size_t)c * HW + gy * WIDTH + gx];
    xh[XH_IDX(p, c >> 3) + (c & 7)] = f2bf(v);
  }
  for (int i = tid; i < 12 * 64; i += 256) {
    int p = 324 + (i >> 6), c = i & 63;
    xh[XH_IDX(p, c >> 3) + (c & 7)] = 0;
  }
  for (int i = tid; i < 1728; i += 256) wdws[i] = f2bf(wdw[i]);
  __syncthreads();
  // LN rsqrt(var) per halo pixel (from bf16)
  for (int p = tid; p < 324; p += 256) {
    float s = 0.f, s2 = 0.f;
    #pragma unroll
    for (int g = 0; g < 8; ++g) {
      short8v v8 = *(const short8v*)&xh[XH_IDX(p, g)];
      #pragma unroll
      for (int j = 0; j < 8; ++j) { float v = bf2f((unsigned short)v8[j]); s += v; s2 += v * v; }
    }
    float mean = s * 0.015625f;
    float var = s2 * 0.015625f - mean * mean;
    rsp[p] = rsqrtf(var + 1e-5f);
  }
  __syncthreads();

  const int lane = tid & 63;
  const int wid = tid >> 6;
  const int fcol = lane & 15;   // MFMA col / A-row lane index
  const int fk = lane >> 4;     // MFMA k-group

  // 1x1 conv chunk via MFMA: out rows [wbase, wbase+16), ln2w folded into weights, rsp in epilogue
  auto gemm_chunk = [&](int wbase) {
    short8v bf[2];
    const float* wr = w1 + (size_t)(wbase + fcol) * 64;
    #pragma unroll
    for (int s = 0; s < 2; ++s) {
      int cs = fk * 8 + s * 32;
      #pragma unroll
      for (int j = 0; j < 8; ++j)
        bf[s][j] = (short)f2bf(wr[cs + j] * ln2w[cs + j]);
    }
    for (int t = wid; t < 21; t += 4) {
      int ar = t * 16 + fcol;
      short8v a0 = *(const short8v*)&xh[XH_IDX(ar, fk)];
      short8v a1 = *(const short8v*)&xh[XH_IDX(ar, fk + 4)];
      f32x4 acc = {0.f, 0.f, 0.f, 0.f};
      acc = __builtin_amdgcn_mfma_f32_16x16x32_bf16(a0, bf[0], acc, 0, 0, 0);
      acc = __builtin_amdgcn_mfma_f32_16x16x32_bf16(a1, bf[1], acc, 0, 0, 0);
      #pragma unroll
      for (int r = 0; r < 4; ++r) {
        int px = t * 16 + fk * 4 + r;
        if (px < 324) tb[fcol * 344 + px] = f2bf(acc[r] * rsp[px]);
      }
    }
  };

  float dout[16];
  auto dw_chunk = [&](int wbase) {
    int py = tid >> 4, px = tid & 15;
    #pragma unroll
    for (int oc = 0; oc < 16; ++oc) {
      const unsigned short* w9 = &wdws[(wbase + oc) * 9];
      const unsigned short* tbr = &tb[oc * 344];
      float a = 0.f;
      #pragma unroll
      for (int ky = 0; ky < 3; ++ky) {
        int rb = (py + ky) * 18 + px;
        a += bf2f(w9[ky*3+0]) * bf2f(tbr[rb]);
        a += bf2f(w9[ky*3+1]) * bf2f(tbr[rb + 1]);
        a += bf2f(w9[ky*3+2]) * bf2f(tbr[rb + 2]);
      }
      dout[oc] = a;
    }
  };

  for (int n = 0; n < 4; ++n) {
    gemm_chunk(16 * n);                 // q head n
    __syncthreads();
    dw_chunk(16 * n);
    #pragma unroll
    for (int oc = 0; oc < 16; ++oc) qc[QC_IDX(oc, tid)] = f2bf(dout[oc]);
    __syncthreads();
    {
      int ch = tid >> 4, seg = tid & 15;
      float s = 0.f;
      #pragma unroll
      for (int j = 0; j < 16; ++j) { float v = bf2f(qc[QC_IDX(ch, seg * 16 + j)]); s += v * v; }
      s += __shfl_xor(s, 1); s += __shfl_xor(s, 2); s += __shfl_xor(s, 4); s += __shfl_xor(s, 8);
      if (seg == 0) Nqp[(size_t)blk * 64 + n * 16 + ch] = s;
    }
    gemm_chunk(64 + 16 * n);            // k head n
    __syncthreads();
    dw_chunk(64 + 16 * n);
    #pragma unroll
    for (int oc = 0; oc < 16; ++oc) kc[QC_IDX(oc, tid)] = f2bf(dout[oc]);
    __syncthreads();
    {
      int ch = tid >> 4, seg = tid & 15;
      float s = 0.f;
      #pragma unroll
      for (int j = 0; j < 16; ++j) { float v = bf2f(kc[QC_IDX(ch, seg * 16 + j)]); s += v * v; }
      s += __shfl_xor(s, 1); s += __shfl_xor(s, 2); s += __shfl_xor(s, 4); s += __shfl_xor(s, 8);
      if (seg == 0) Nkp[(size_t)blk * 64 + n * 16 + ch] = s;
    }
    if (wid == 0) {                     // Gram_n = q_n @ k_n^T over 256 px (MFMA, K=256)
      f32x4 g = {0.f, 0.f, 0.f, 0.f};
      #pragma unroll
      for (int s = 0; s < 8; ++s) {
        int G = fk + 4 * s;
        short8v aq = *(const short8v*)&qc[QCG_IDX(fcol, G)];
        short8v bk = *(const short8v*)&kc[QCG_IDX(fcol, G)];
        g = __builtin_amdgcn_mfma_f32_16x16x32_bf16(aq, bk, g, 0, 0, 0);
      }
      float* gp = Gp + ((size_t)blk * 4 + n) * 256;
      #pragma unroll
      for (int r = 0; r < 4; ++r) gp[(fk * 4 + r) * 16 + fcol] = g[r];
    }
  }
  // v chunks: dw -> *illu -> store vm
  const float* ib = illu + (size_t)b * 64 * HW;
  for (int j = 0; j < 4; ++j) {
    gemm_chunk(128 + 16 * j);
    __syncthreads();
    dw_chunk(128 + 16 * j);
    int gy = ty0 + (tid >> 4), gx = tx0 + (tid & 15);
    size_t ppos = (size_t)gy * WIDTH + gx;
    #pragma unroll
    for (int oc = 0; oc < 16; ++oc) {
      int vc = 16 * j + oc;
      float iv = ib[(size_t)vc * HW + ppos];
      vm[((size_t)b * 64 + vc) * HW + ppos] = f2bf(dout[oc] * iv);
    }
    __syncthreads();
  }
}

// ---------------- two-stage deterministic reduction -> softmax -> fold w_out into M ----------------
__global__ __launch_bounds__(256) void k_reduce1(
    const float* __restrict__ Gp, const float* __restrict__ Nqp, const float* __restrict__ Nkp,
    float* __restrict__ G2, float* __restrict__ Nq2, float* __restrict__ Nk2)
{
  const int blk = blockIdx.x;
  const int b = blk >> 5, g = blk & 31;
  const int tid = threadIdx.x;
  float ga[4] = {0.f, 0.f, 0.f, 0.f};
  for (int t = 0; t < 8; ++t) {
    const float* src = Gp + ((size_t)(b * 256 + g * 8 + t)) * 1024;
    #pragma unroll
    for (int j = 0; j < 4; ++j) ga[j] += src[tid + j * 256];
  }
  float* dst = G2 + ((size_t)(b * 32 + g)) * 1024;
  #pragma unroll
  for (int j = 0; j < 4; ++j) dst[tid + j * 256] = ga[j];
  if (tid < 128) {
    int ch = tid & 63; bool isq = tid < 64;
    const float* np = isq ? Nqp : Nkp;
    float s = 0.f;
    for (int t = 0; t < 8; ++t) s += np[((size_t)(b * 256 + g * 8 + t)) * 64 + ch];
    (isq ? Nq2 : Nk2)[(size_t)(b * 32 + g) * 64 + ch] = s;
  }
}

__global__ __launch_bounds__(256) void k_reduce2(
    const float* __restrict__ G2, const float* __restrict__ Nq2, const float* __restrict__ Nk2,
    const float* __restrict__ temp, const float* __restrict__ wout, float* __restrict__ M)
{
  __shared__ float Gs[1024];
  __shared__ float As[4][16][17];
  __shared__ float nq[64], nk[64];
  const int b = blockIdx.x;
  const int tid = threadIdx.x;
  float ga[4] = {0.f, 0.f, 0.f, 0.f};
  for (int g = 0; g < 32; ++g) {
    const float* src = G2 + ((size_t)(b * 32 + g)) * 1024;
    #pragma unroll
    for (int j = 0; j < 4; ++j) ga[j] += src[tid + j * 256];
  }
  #pragma unroll
  for (int j = 0; j < 4; ++j) Gs[tid + j * 256] = ga[j];
  if (tid < 128) {
    int ch = tid & 63; bool isq = tid < 64;
    const float* n2 = isq ? Nq2 : Nk2;
    float s = 0.f;
    for (int g = 0; g < 32; ++g) s += n2[(size_t)(b * 32 + g) * 64 + ch];
    float r = fmaxf(sqrtf(s), 1e-12f);
    (isq ? nq : nk)[ch] = r;
  }
  __syncthreads();
  if (tid < 64) {
    int n = tid >> 4, d = tid & 15;
    float tv = temp[n];
    float row[16]; float mx = -1e30f;
    #pragma unroll
    for (int e = 0; e < 16; ++e) {
      float v = Gs[n * 256 + d * 16 + e] / (nq[n * 16 + d] * nk[n * 16 + e]) * tv;
      row[e] = v; mx = fmaxf(mx, v);
    }
    float s = 0.f;
    #pragma unroll
    for (int e = 0; e < 16; ++e) { float ev = __expf(row[e] - mx); row[e] = ev; s += ev; }
    float inv = 1.f / s;
    #pragma unroll
    for (int e = 0; e < 16; ++e) As[n][d][e] = row[e] * inv;
  }
  __syncthreads();
  float* Mb = M + (size_t)b * 4096;
  for (int i = tid; i < 4096; i += 256) {
    int o = i >> 6, cp = i & 63;
    int n = cp >> 4, e = cp & 15;
    float a = 0.f;
    #pragma unroll
    for (int d = 0; d < 16; ++d) a += wout[o * 64 + n * 16 + d] * As[n][d][e];
    Mb[i] = a;
  }
}

// ---------------- apply M to vm, accumulate into out ----------------
// block = 256 pixels; vm column in registers, M broadcast from LDS
__global__ __launch_bounds__(256, 3) void k_mdta_out(
    const unsigned short* __restrict__ vm, const float* __restrict__ M,
    float* __restrict__ out)
{
  __shared__ __align__(16) float Ml[4096];
  __shared__ __align__(16) unsigned short vml[64 * 260];
  const int blk = blockIdx.x;
  const int b = blk >> 8;
  const int pix0 = (blk & 255) << 8;
  const int tid = threadIdx.x;

  const float* Mb = M + (size_t)b * 4096;
  for (int i = tid; i < 4096; i += 256) Ml[i] = Mb[i];
  const unsigned short* vb = vm + (size_t)b * 64 * HW;
  for (int i = tid; i < 16384; i += 256) {
    int c = i >> 8, p = i & 255;
    vml[c * 260 + p] = vb[(size_t)c * HW + pix0 + p];
  }
  __syncthreads();
  float xcol[64];
  #pragma unroll
  for (int c = 0; c < 64; ++c) xcol[c] = bf2f(vml[c * 260 + tid]);
  float* ob = out + (size_t)b * 64 * HW + pix0 + tid;
  for (int o = 0; o < 64; ++o) {
    const float4* mr = (const float4*)&Ml[o * 64];
    float acc = 0.f;
    #pragma unroll
    for (int g = 0; g < 16; ++g) {
      float4 m4 = mr[g];
      acc += m4.x * xcol[g*4] + m4.y * xcol[g*4+1] + m4.z * xcol[g*4+2] + m4.w * xcol[g*4+3];
    }
    ob[(size_t)o * HW] += acc;
  }
}

extern "C" void kernel_launch(void* const* d_in, const int* in_sizes, int n_in,
                              void* d_out, int out_size, void* d_ws, size_t ws_size,
                              hipStream_t stream) {
  const float* x     = (const float*)d_in[0];
  const float* illu  = (const float*)d_in[1];
  const float* ln1w  = (const float*)d_in[2];
  const float* ln2w  = (const float*)d_in[3];
  const float* wqkv  = (const float*)d_in[4];
  const float* bqkv  = (const float*)d_in[5];
  const float* rpb   = (const float*)d_in[6];
  const float* wproj = (const float*)d_in[7];
  const float* bproj = (const float*)d_in[8];
  const float* temp  = (const float*)d_in[9];
  const float* w1    = (const float*)d_in[10];
  const float* wdw   = (const float*)d_in[11];
  const float* wout  = (const float*)d_in[12];
  float* out = (float*)d_out;

  char* ws = (char*)d_ws;
  unsigned short* vm = (unsigned short*)ws;            // 67,108,864 B
  float* Gp  = (float*)(ws + 67108864);                //  8,388,608 B
  float* Nqp = (float*)(ws + 75497472);                //    524,288 B
  float* Nkp = (float*)(ws + 76021760);                //    524,288 B
  float* G2  = (float*)(ws + 76546048);                //  1,048,576 B
  float* Nq2 = (float*)(ws + 77594624);                //     65,536 B
  float* Nk2 = (float*)(ws + 77660160);                //     65,536 B
  float* M   = (float*)(ws + 77725696);                //    131,072 B

  k_spatial<<<8192, 256, 0, stream>>>(x, illu, ln1w, wqkv, bqkv, rpb, wproj, bproj, out);
  k_chan_qkv<<<2048, 256, 0, stream>>>(x, illu, ln2w, w1, wdw, vm, Gp, Nqp, Nkp);
  k_reduce1<<<256, 256, 0, stream>>>(Gp, Nqp, Nkp, G2, Nq2, Nk2);
  k_reduce2<<<8, 256, 0, stream>>>(G2, Nq2, Nk2, temp, wout, M);
  k_mdta_out<<<2048, 256, 0, stream>>>(vm, M, out);
}

// Round 6
// 1185.446 us; speedup vs baseline: 3.8600x; 1.3320x over previous
//
#include <hip/hip_runtime.h>
#include <hip/hip_bf16.h>

#define HW 65536
#define WIDTH 256

typedef __attribute__((ext_vector_type(8))) short short8v;
typedef __attribute__((ext_vector_type(4))) short short4v;
typedef __attribute__((ext_vector_type(4))) float f32x4;

__device__ inline float bf2f(unsigned short u) {
  unsigned int i = ((unsigned int)u) << 16;
  float f; __builtin_memcpy(&f, &i, 4); return f;
}
__device__ inline unsigned short f2bf(float x) {
  __hip_bfloat16 h = __float2bfloat16(x);
  unsigned short u; __builtin_memcpy(&u, &h, 2); return u;
}

// swizzled LDS indexers for k_chan_qkv (granule = 8 bf16 = 16B)
#define XH_IDX(p, g) ((p)*64 + ((((g) ^ ((p)&7)))<<3))
#define QC_IDX(ch, px) ((ch)*256 + ((((px)>>3) ^ ((ch)&7))<<3) + ((px)&7))
#define QCG_IDX(ch, G) ((ch)*256 + ((((G) ^ ((ch)&7)))<<3))

// ---------------- Spatial window-attention branch ----------------
// one workgroup = one 8x8 window (8192 WGs), 256 threads, MFMA qkv/proj,
// XCD-swizzled so x-adjacent windows (sharing cachelines) land on one XCD.
__global__ __launch_bounds__(256, 2) void k_spatial(
    const float* __restrict__ x, const float* __restrict__ illu,
    const float* __restrict__ ln1w, const float* __restrict__ wqkv,
    const float* __restrict__ bqkv, const float* __restrict__ rpb,
    const float* __restrict__ wproj, const float* __restrict__ bproj,
    float* __restrict__ out)
{
  __shared__ __align__(16) unsigned short xw[64*72];   // raw x window bf16 -> illu
  __shared__ __align__(16) unsigned short qs[64*72];   // q (scaled) -> attn out
  __shared__ __align__(16) unsigned short ks[64*72];   // k -> proj out (bf16)
  __shared__ __align__(16) unsigned short vs[64*72];   // v (illu-modulated)
  __shared__ __align__(16) unsigned short wq[192*72];  // w_qkv^T*ln1w bf16 [out][c] -> wproj^T [o][c]
  __shared__ float rpbs[900];
  __shared__ float bq_s[192];
  __shared__ float rs_tok[64];

  const int tid = threadIdx.x;
  // XCD swizzle: XCD k processes logical blocks [k*1024, (k+1)*1024) in order
  const int lb = ((blockIdx.x & 7) << 10) | (blockIdx.x >> 3);
  const int b = lb >> 10;
  const int win = lb & 1023;
  const int h0 = (win >> 5) << 3;
  const int w0 = (win & 31) << 3;
  const float* xb = x + (size_t)b * 64 * HW;

  const int lane = tid & 63;
  const int w = tid >> 6;         // wave id = head id
  const int fr = lane & 15;       // MFMA row/col-in-tile
  const int fg = lane >> 4;       // MFMA k-group

  for (int i = tid; i < 900; i += 256) rpbs[i] = rpb[i];
  for (int i = tid; i < 192; i += 256) bq_s[i] = bqkv[i];
  // w_qkv folded with ln1w, stored transposed [o][c] (B-frag layout)
  for (int i = tid; i < 12288; i += 256) {
    int c = i / 192, o = i - c * 192;
    wq[o*72 + c] = f2bf(wqkv[i] * ln1w[c]);
  }
  // x window, float4 loads
  for (int i = tid; i < 1024; i += 256) {
    int c = i >> 4, seg = i & 15;
    int row = seg >> 1, half = (seg & 1) * 4;
    float4 v4 = *(const float4*)&xb[(size_t)c * HW + (h0 + row) * WIDTH + w0 + half];
    int p = row * 8 + half;
    xw[(p+0)*72 + c] = f2bf(v4.x);
    xw[(p+1)*72 + c] = f2bf(v4.y);
    xw[(p+2)*72 + c] = f2bf(v4.z);
    xw[(p+3)*72 + c] = f2bf(v4.w);
  }
  __syncthreads();
  // LN stats per token (rsqrt folded into qkv epilogue)
  {
    int l = tid >> 2, q4 = tid & 3;
    short8v v8a = *(const short8v*)&xw[l*72 + q4*16];
    short8v v8b = *(const short8v*)&xw[l*72 + q4*16 + 8];
    float s = 0.f, s2 = 0.f;
    #pragma unroll
    for (int j = 0; j < 8; ++j) {
      float va = bf2f((unsigned short)v8a[j]), vb = bf2f((unsigned short)v8b[j]);
      s += va + vb; s2 += va * va + vb * vb;
    }
    s += __shfl_down(s, 1); s2 += __shfl_down(s2, 1);
    s += __shfl_down(s, 2); s2 += __shfl_down(s2, 2);
    if (q4 == 0) {
      float mean = s * 0.015625f;
      float var = s2 * 0.015625f - mean * mean;
      rs_tok[l] = rsqrtf(var + 1e-5f);
    }
  }
  __syncthreads();
  // qkv GEMM via MFMA: M=64 tok, K=64 ch, wave w computes cols of head w for q,k,v
  {
    short8v a[4][2];
    #pragma unroll
    for (int rt = 0; rt < 4; ++rt)
      #pragma unroll
      for (int kh = 0; kh < 2; ++kh)
        a[rt][kh] = *(const short8v*)&xw[(rt*16 + fr)*72 + kh*32 + fg*8];
    #pragma unroll
    for (int part = 0; part < 3; ++part) {
      int ob = part * 64 + w * 16;
      short8v b0 = *(const short8v*)&wq[(ob + fr)*72 + fg*8];
      short8v b1 = *(const short8v*)&wq[(ob + fr)*72 + 32 + fg*8];
      float bias = bq_s[ob + fr];
      #pragma unroll
      for (int rt = 0; rt < 4; ++rt) {
        f32x4 acc = {0.f, 0.f, 0.f, 0.f};
        acc = __builtin_amdgcn_mfma_f32_16x16x32_bf16(a[rt][0], b0, acc, 0, 0, 0);
        acc = __builtin_amdgcn_mfma_f32_16x16x32_bf16(a[rt][1], b1, acc, 0, 0, 0);
        #pragma unroll
        for (int r = 0; r < 4; ++r) {
          int t = rt*16 + fg*4 + r;
          float val = acc[r] * rs_tok[t] + bias;
          if (part == 0)      qs[t*72 + w*16 + fr] = f2bf(val * 0.25f);
          else if (part == 1) ks[t*72 + w*16 + fr] = f2bf(val);
          else                vs[t*72 + w*16 + fr] = f2bf(val);
        }
      }
    }
  }
  __syncthreads();
  // stage illu -> xw and wproj^T -> wq[0..64*72)
  {
    const float* ib = illu + (size_t)b * 64 * HW;
    for (int i = tid; i < 1024; i += 256) {
      int c = i >> 4, seg = i & 15;
      int row = seg >> 1, half = (seg & 1) * 4;
      float4 v4 = *(const float4*)&ib[(size_t)c * HW + (h0 + row) * WIDTH + w0 + half];
      int p = row * 8 + half;
      xw[(p+0)*72 + c] = f2bf(v4.x);
      xw[(p+1)*72 + c] = f2bf(v4.y);
      xw[(p+2)*72 + c] = f2bf(v4.z);
      xw[(p+3)*72 + c] = f2bf(v4.w);
    }
    for (int i = tid; i < 4096; i += 256) {
      int c = i >> 6, o = i & 63;
      wq[o*72 + c] = f2bf(wproj[i]);
    }
  }
  __syncthreads();
  // illumination modulation of V
  for (int i = tid; i < 4096; i += 256) {
    int l = i >> 6, c = i & 63;
    vs[l*72 + c] = f2bf(bf2f(vs[l*72 + c]) * bf2f(xw[l*72 + c]));
  }
  __syncthreads();
  // attention: wave = head, lane = query token (scalar, bf16 LDS)
  {
    int hb = w * 16;
    int l = lane;
    float qrow[16];
    {
      short8v q0 = *(const short8v*)&qs[l*72 + hb];
      short8v q1 = *(const short8v*)&qs[l*72 + hb + 8];
      #pragma unroll
      for (int d = 0; d < 8; ++d) { qrow[d] = bf2f((unsigned short)q0[d]); qrow[d+8] = bf2f((unsigned short)q1[d]); }
    }
    float arow[64];
    int li = l >> 3, lj = l & 7;
    float mx = -1e30f;
    #pragma unroll 4
    for (int m = 0; m < 64; ++m) {
      short8v k0 = *(const short8v*)&ks[m*72 + hb];
      short8v k1 = *(const short8v*)&ks[m*72 + hb + 8];
      float s = 0.f;
      #pragma unroll
      for (int d = 0; d < 8; ++d) s += qrow[d] * bf2f((unsigned short)k0[d]) + qrow[d+8] * bf2f((unsigned short)k1[d]);
      int ridx = (li - (m >> 3) + 7) * 15 + (lj - (m & 7) + 7);
      s += rpbs[ridx * 4 + w];
      arow[m] = s;
      mx = fmaxf(mx, s);
    }
    float ssum = 0.f;
    #pragma unroll
    for (int m = 0; m < 64; ++m) { float e = __expf(arow[m] - mx); arow[m] = e; ssum += e; }
    float inv = 1.f / ssum;
    float acc[16];
    #pragma unroll
    for (int d = 0; d < 16; ++d) acc[d] = 0.f;
    #pragma unroll 4
    for (int m = 0; m < 64; ++m) {
      short8v v0 = *(const short8v*)&vs[m*72 + hb];
      short8v v1 = *(const short8v*)&vs[m*72 + hb + 8];
      float a = arow[m];
      #pragma unroll
      for (int d = 0; d < 8; ++d) { acc[d] += a * bf2f((unsigned short)v0[d]); acc[d+8] += a * bf2f((unsigned short)v1[d]); }
    }
    #pragma unroll
    for (int d = 0; d < 16; ++d) qs[l*72 + hb + d] = f2bf(acc[d] * inv);
  }
  __syncthreads();
  // proj via MFMA: A = attn-out (qs), B = wproj^T (wq); result bf16 -> ks
  {
    short8v a[4][2];
    #pragma unroll
    for (int rt = 0; rt < 4; ++rt)
      #pragma unroll
      for (int kh = 0; kh < 2; ++kh)
        a[rt][kh] = *(const short8v*)&qs[(rt*16 + fr)*72 + kh*32 + fg*8];
    short8v b0 = *(const short8v*)&wq[(w*16 + fr)*72 + fg*8];
    short8v b1 = *(const short8v*)&wq[(w*16 + fr)*72 + 32 + fg*8];
    #pragma unroll
    for (int rt = 0; rt < 4; ++rt) {
      f32x4 acc = {0.f, 0.f, 0.f, 0.f};
      acc = __builtin_amdgcn_mfma_f32_16x16x32_bf16(a[rt][0], b0, acc, 0, 0, 0);
      acc = __builtin_amdgcn_mfma_f32_16x16x32_bf16(a[rt][1], b1, acc, 0, 0, 0);
      #pragma unroll
      for (int r = 0; r < 4; ++r) {
        int t = rt*16 + fg*4 + r;
        ks[t*72 + w*16 + fr] = f2bf(acc[r]);
      }
    }
  }
  __syncthreads();
  // final: residual + bias + store, float4
  for (int i = tid; i < 1024; i += 256) {
    int o = i >> 4, seg = i & 15;
    int row = seg >> 1, half = (seg & 1) * 4;
    int p = row * 8 + half;
    size_t gofs = (size_t)o * HW + (h0 + row) * WIDTH + w0 + half;
    float4 xr4 = *(const float4*)&xb[gofs];
    float bp = bproj[o];
    float4 r;
    r.x = xr4.x + bp + bf2f(ks[(p+0)*72 + o]);
    r.y = xr4.y + bp + bf2f(ks[(p+1)*72 + o]);
    r.z = xr4.z + bp + bf2f(ks[(p+2)*72 + o]);
    r.w = xr4.w + bp + bf2f(ks[(p+3)*72 + o]);
    *(float4*)&out[(size_t)b * 64 * HW + gofs] = r;
  }
}

// ---------------- Channel branch producer: LN2 + 1x1 (MFMA) + dw3x3 + Gram (MFMA) ----------------
__global__ __launch_bounds__(256, 2) void k_chan_qkv(
    const float* __restrict__ x, const float* __restrict__ illu,
    const float* __restrict__ ln2w, const float* __restrict__ w1,
    const float* __restrict__ wdw,
    unsigned short* __restrict__ vm, float* __restrict__ Gp,
    float* __restrict__ Nqp, float* __restrict__ Nkp)
{
  __shared__ __align__(16) unsigned short xh[336*64];
  __shared__ __align__(16) unsigned short tb[16*344];
  __shared__ __align__(16) unsigned short qc[16*256];
  __shared__ __align__(16) unsigned short kc[16*256];
  __shared__ float rsp[324];
  __shared__ unsigned short wdws[1728];

  const int tid = threadIdx.x;
  const int blk = blockIdx.x;
  const int b = blk >> 8;
  const int tile = blk & 255;
  const int ty0 = (tile >> 4) << 4, tx0 = (tile & 15) << 4;
  const float* xb = x + (size_t)b * 64 * HW;

  for (int i = tid; i < 64 * 324; i += 256) {
    int c = i / 324, p = i - c * 324;
    int hy = p / 18, hx = p - hy * 18;
    int gy = ty0 + hy - 1, gx = tx0 + hx - 1;
    float v = 0.f;
    if (gy >= 0 && gy < 256 && gx >= 0 && gx < 256)
      v = xb[(size_t)c * HW + gy * WIDTH + gx];
    xh[XH_IDX(p, c >> 3) + (c & 7)] = f2bf(v);
  }
  for (int i = tid; i < 12 * 64; i += 256) {
    int p = 324 + (i >> 6), c = i & 63;
    xh[XH_IDX(p, c >> 3) + (c & 7)] = 0;
  }
  for (int i = tid; i < 1728; i += 256) wdws[i] = f2bf(wdw[i]);
  __syncthreads();
  for (int p = tid; p < 324; p += 256) {
    float s = 0.f, s2 = 0.f;
    #pragma unroll
    for (int g = 0; g < 8; ++g) {
      short8v v8 = *(const short8v*)&xh[XH_IDX(p, g)];
      #pragma unroll
      for (int j = 0; j < 8; ++j) { float v = bf2f((unsigned short)v8[j]); s += v; s2 += v * v; }
    }
    float mean = s * 0.015625f;
    float var = s2 * 0.015625f - mean * mean;
    rsp[p] = rsqrtf(var + 1e-5f);
  }
  __syncthreads();

  const int lane = tid & 63;
  const int wid = tid >> 6;
  const int fcol = lane & 15;
  const int fk = lane >> 4;

  auto gemm_chunk = [&](int wbase) {
    short8v bf[2];
    const float* wr = w1 + (size_t)(wbase + fcol) * 64;
    #pragma unroll
    for (int s = 0; s < 2; ++s) {
      int cs = fk * 8 + s * 32;
      #pragma unroll
      for (int j = 0; j < 8; ++j)
        bf[s][j] = (short)f2bf(wr[cs + j] * ln2w[cs + j]);
    }
    for (int t = wid; t < 21; t += 4) {
      int ar = t * 16 + fcol;
      short8v a0 = *(const short8v*)&xh[XH_IDX(ar, fk)];
      short8v a1 = *(const short8v*)&xh[XH_IDX(ar, fk + 4)];
      f32x4 acc = {0.f, 0.f, 0.f, 0.f};
      acc = __builtin_amdgcn_mfma_f32_16x16x32_bf16(a0, bf[0], acc, 0, 0, 0);
      acc = __builtin_amdgcn_mfma_f32_16x16x32_bf16(a1, bf[1], acc, 0, 0, 0);
      #pragma unroll
      for (int r = 0; r < 4; ++r) {
        int px = t * 16 + fk * 4 + r;
        if (px < 324) tb[fcol * 344 + px] = f2bf(acc[r] * rsp[px]);
      }
    }
  };

  float dout[16];
  auto dw_chunk = [&](int wbase) {
    int py = tid >> 4, px = tid & 15;
    #pragma unroll
    for (int oc = 0; oc < 16; ++oc) {
      const unsigned short* w9 = &wdws[(wbase + oc) * 9];
      const unsigned short* tbr = &tb[oc * 344];
      float a = 0.f;
      #pragma unroll
      for (int ky = 0; ky < 3; ++ky) {
        int rb = (py + ky) * 18 + px;
        a += bf2f(w9[ky*3+0]) * bf2f(tbr[rb]);
        a += bf2f(w9[ky*3+1]) * bf2f(tbr[rb + 1]);
        a += bf2f(w9[ky*3+2]) * bf2f(tbr[rb + 2]);
      }
      dout[oc] = a;
    }
  };

  for (int n = 0; n < 4; ++n) {
    gemm_chunk(16 * n);
    __syncthreads();
    dw_chunk(16 * n);
    #pragma unroll
    for (int oc = 0; oc < 16; ++oc) qc[QC_IDX(oc, tid)] = f2bf(dout[oc]);
    __syncthreads();
    {
      int ch = tid >> 4, seg = tid & 15;
      float s = 0.f;
      #pragma unroll
      for (int j = 0; j < 16; ++j) { float v = bf2f(qc[QC_IDX(ch, seg * 16 + j)]); s += v * v; }
      s += __shfl_xor(s, 1); s += __shfl_xor(s, 2); s += __shfl_xor(s, 4); s += __shfl_xor(s, 8);
      if (seg == 0) Nqp[(size_t)blk * 64 + n * 16 + ch] = s;
    }
    gemm_chunk(64 + 16 * n);
    __syncthreads();
    dw_chunk(64 + 16 * n);
    #pragma unroll
    for (int oc = 0; oc < 16; ++oc) kc[QC_IDX(oc, tid)] = f2bf(dout[oc]);
    __syncthreads();
    {
      int ch = tid >> 4, seg = tid & 15;
      float s = 0.f;
      #pragma unroll
      for (int j = 0; j < 16; ++j) { float v = bf2f(kc[QC_IDX(ch, seg * 16 + j)]); s += v * v; }
      s += __shfl_xor(s, 1); s += __shfl_xor(s, 2); s += __shfl_xor(s, 4); s += __shfl_xor(s, 8);
      if (seg == 0) Nkp[(size_t)blk * 64 + n * 16 + ch] = s;
    }
    if (wid == 0) {
      f32x4 g = {0.f, 0.f, 0.f, 0.f};
      #pragma unroll
      for (int s = 0; s < 8; ++s) {
        int G = fk + 4 * s;
        short8v aq = *(const short8v*)&qc[QCG_IDX(fcol, G)];
        short8v bk = *(const short8v*)&kc[QCG_IDX(fcol, G)];
        g = __builtin_amdgcn_mfma_f32_16x16x32_bf16(aq, bk, g, 0, 0, 0);
      }
      float* gp = Gp + ((size_t)blk * 4 + n) * 256;
      #pragma unroll
      for (int r = 0; r < 4; ++r) gp[(fk * 4 + r) * 16 + fcol] = g[r];
    }
  }
  const float* ib = illu + (size_t)b * 64 * HW;
  for (int j = 0; j < 4; ++j) {
    gemm_chunk(128 + 16 * j);
    __syncthreads();
    dw_chunk(128 + 16 * j);
    int gy = ty0 + (tid >> 4), gx = tx0 + (tid & 15);
    size_t ppos = (size_t)gy * WIDTH + gx;
    #pragma unroll
    for (int oc = 0; oc < 16; ++oc) {
      int vc = 16 * j + oc;
      float iv = ib[(size_t)vc * HW + ppos];
      vm[((size_t)b * 64 + vc) * HW + ppos] = f2bf(dout[oc] * iv);
    }
    __syncthreads();
  }
}

// ---------------- two-stage deterministic reduction -> softmax -> fold w_out into M ----------------
__global__ __launch_bounds__(256) void k_reduce1(
    const float* __restrict__ Gp, const float* __restrict__ Nqp, const float* __restrict__ Nkp,
    float* __restrict__ G2, float* __restrict__ Nq2, float* __restrict__ Nk2)
{
  const int blk = blockIdx.x;
  const int b = blk >> 5, g = blk & 31;
  const int tid = threadIdx.x;
  float ga[4] = {0.f, 0.f, 0.f, 0.f};
  for (int t = 0; t < 8; ++t) {
    const float* src = Gp + ((size_t)(b * 256 + g * 8 + t)) * 1024;
    #pragma unroll
    for (int j = 0; j < 4; ++j) ga[j] += src[tid + j * 256];
  }
  float* dst = G2 + ((size_t)(b * 32 + g)) * 1024;
  #pragma unroll
  for (int j = 0; j < 4; ++j) dst[tid + j * 256] = ga[j];
  if (tid < 128) {
    int ch = tid & 63; bool isq = tid < 64;
    const float* np = isq ? Nqp : Nkp;
    float s = 0.f;
    for (int t = 0; t < 8; ++t) s += np[((size_t)(b * 256 + g * 8 + t)) * 64 + ch];
    (isq ? Nq2 : Nk2)[(size_t)(b * 32 + g) * 64 + ch] = s;
  }
}

__global__ __launch_bounds__(256) void k_reduce2(
    const float* __restrict__ G2, const float* __restrict__ Nq2, const float* __restrict__ Nk2,
    const float* __restrict__ temp, const float* __restrict__ wout, float* __restrict__ M)
{
  __shared__ float Gs[1024];
  __shared__ float As[4][16][17];
  __shared__ float nq[64], nk[64];
  const int b = blockIdx.x;
  const int tid = threadIdx.x;
  float ga[4] = {0.f, 0.f, 0.f, 0.f};
  for (int g = 0; g < 32; ++g) {
    const float* src = G2 + ((size_t)(b * 32 + g)) * 1024;
    #pragma unroll
    for (int j = 0; j < 4; ++j) ga[j] += src[tid + j * 256];
  }
  #pragma unroll
  for (int j = 0; j < 4; ++j) Gs[tid + j * 256] = ga[j];
  if (tid < 128) {
    int ch = tid & 63; bool isq = tid < 64;
    const float* n2 = isq ? Nq2 : Nk2;
    float s = 0.f;
    for (int g = 0; g < 32; ++g) s += n2[(size_t)(b * 32 + g) * 64 + ch];
    float r = fmaxf(sqrtf(s), 1e-12f);
    (isq ? nq : nk)[ch] = r;
  }
  __syncthreads();
  if (tid < 64) {
    int n = tid >> 4, d = tid & 15;
    float tv = temp[n];
    float row[16]; float mx = -1e30f;
    #pragma unroll
    for (int e = 0; e < 16; ++e) {
      float v = Gs[n * 256 + d * 16 + e] / (nq[n * 16 + d] * nk[n * 16 + e]) * tv;
      row[e] = v; mx = fmaxf(mx, v);
    }
    float s = 0.f;
    #pragma unroll
    for (int e = 0; e < 16; ++e) { float ev = __expf(row[e] - mx); row[e] = ev; s += ev; }
    float inv = 1.f / s;
    #pragma unroll
    for (int e = 0; e < 16; ++e) As[n][d][e] = row[e] * inv;
  }
  __syncthreads();
  float* Mb = M + (size_t)b * 4096;
  for (int i = tid; i < 4096; i += 256) {
    int o = i >> 6, cp = i & 63;
    int n = cp >> 4, e = cp & 15;
    float a = 0.f;
    #pragma unroll
    for (int d = 0; d < 16; ++d) a += wout[o * 64 + n * 16 + d] * As[n][d][e];
    Mb[i] = a;
  }
}

// ---------------- apply M to vm, accumulate into out ----------------
__global__ __launch_bounds__(256, 3) void k_mdta_out(
    const unsigned short* __restrict__ vm, const float* __restrict__ M,
    float* __restrict__ out)
{
  __shared__ __align__(16) float Ml[4096];
  __shared__ __align__(16) unsigned short vml[64 * 260];
  const int blk = blockIdx.x;
  const int b = blk >> 8;
  const int pix0 = (blk & 255) << 8;
  const int tid = threadIdx.x;

  const float* Mb = M + (size_t)b * 4096;
  for (int i = tid; i < 4096; i += 256) Ml[i] = Mb[i];
  const unsigned short* vb = vm + (size_t)b * 64 * HW;
  for (int i = tid; i < 16384; i += 256) {
    int c = i >> 8, p = i & 255;
    vml[c * 260 + p] = vb[(size_t)c * HW + pix0 + p];
  }
  __syncthreads();
  float xcol[64];
  #pragma unroll
  for (int c = 0; c < 64; ++c) xcol[c] = bf2f(vml[c * 260 + tid]);
  float* ob = out + (size_t)b * 64 * HW + pix0 + tid;
  for (int o = 0; o < 64; ++o) {
    const float4* mr = (const float4*)&Ml[o * 64];
    float acc = 0.f;
    #pragma unroll
    for (int g = 0; g < 16; ++g) {
      float4 m4 = mr[g];
      acc += m4.x * xcol[g*4] + m4.y * xcol[g*4+1] + m4.z * xcol[g*4+2] + m4.w * xcol[g*4+3];
    }
    ob[(size_t)o * HW] += acc;
  }
}

extern "C" void kernel_launch(void* const* d_in, const int* in_sizes, int n_in,
                              void* d_out, int out_size, void* d_ws, size_t ws_size,
                              hipStream_t stream) {
  const float* x     = (const float*)d_in[0];
  const float* illu  = (const float*)d_in[1];
  const float* ln1w  = (const float*)d_in[2];
  const float* ln2w  = (const float*)d_in[3];
  const float* wqkv  = (const float*)d_in[4];
  const float* bqkv  = (const float*)d_in[5];
  const float* rpb   = (const float*)d_in[6];
  const float* wproj = (const float*)d_in[7];
  const float* bproj = (const float*)d_in[8];
  const float* temp  = (const float*)d_in[9];
  const float* w1    = (const float*)d_in[10];
  const float* wdw   = (const float*)d_in[11];
  const float* wout  = (const float*)d_in[12];
  float* out = (float*)d_out;

  char* ws = (char*)d_ws;
  unsigned short* vm = (unsigned short*)ws;            // 67,108,864 B
  float* Gp  = (float*)(ws + 67108864);                //  8,388,608 B
  float* Nqp = (float*)(ws + 75497472);                //    524,288 B
  float* Nkp = (float*)(ws + 76021760);                //    524,288 B
  float* G2  = (float*)(ws + 76546048);                //  1,048,576 B
  float* Nq2 = (float*)(ws + 77594624);                //     65,536 B
  float* Nk2 = (float*)(ws + 77660160);                //     65,536 B
  float* M   = (float*)(ws + 77725696);                //    131,072 B

  k_spatial<<<8192, 256, 0, stream>>>(x, illu, ln1w, wqkv, bqkv, rpb, wproj, bproj, out);
  k_chan_qkv<<<2048, 256, 0, stream>>>(x, illu, ln2w, w1, wdw, vm, Gp, Nqp, Nkp);
  k_reduce1<<<256, 256, 0, stream>>>(Gp, Nqp, Nkp, G2, Nq2, Nk2);
  k_reduce2<<<8, 256, 0, stream>>>(G2, Nq2, Nk2, temp, wout, M);
  k_mdta_out<<<2048, 256, 0, stream>>>(vm, M, out);
}

// Round 7
// 815.212 us; speedup vs baseline: 5.6130x; 1.4542x over previous
//
#include <hip/hip_runtime.h>
#include <hip/hip_bf16.h>

#define HW 65536
#define WIDTH 256
#define SP_OFF 77856768ull   // ws offset of spatial-out blob (67,108,864 B bf16)

typedef __attribute__((ext_vector_type(8))) short short8v;
typedef __attribute__((ext_vector_type(4))) short short4v;
typedef __attribute__((ext_vector_type(4))) float f32x4;

__device__ inline float bf2f(unsigned short u) {
  unsigned int i = ((unsigned int)u) << 16;
  float f; __builtin_memcpy(&f, &i, 4); return f;
}
__device__ inline unsigned short f2bf(float x) {
  __hip_bfloat16 h = __float2bfloat16(x);
  unsigned short u; __builtin_memcpy(&u, &h, 2); return u;
}

// swizzled LDS indexers for k_chan_qkv (granule = 8 bf16 = 16B)
#define XH_IDX(p, g) ((p)*64 + ((((g) ^ ((p)&7)))<<3))
#define QC_IDX(ch, px) ((ch)*256 + ((((px)>>3) ^ ((ch)&7))<<3) + ((px)&7))
#define QCG_IDX(ch, G) ((ch)*256 + ((((G) ^ ((ch)&7)))<<3))

// ---------------- Spatial window-attention branch ----------------
// one WG = one 8x8 window; MFMA qkv/attention/proj; XCD-swizzled blocks;
// output either bf16 window-major blob in ws (use_sp) or direct f32.
__global__ __launch_bounds__(256, 2) void k_spatial(
    const float* __restrict__ x, const float* __restrict__ illu,
    const float* __restrict__ ln1w, const float* __restrict__ wqkv,
    const float* __restrict__ bqkv, const float* __restrict__ rpb,
    const float* __restrict__ wproj, const float* __restrict__ bproj,
    float* __restrict__ out, unsigned short* __restrict__ sp, int use_sp)
{
  __shared__ __align__(16) unsigned short shbuf[9216]; // xw | qs, later 4x P-buffers
  __shared__ __align__(16) unsigned short ks[64*72];   // K -> attn-out
  __shared__ __align__(16) unsigned short vs[64*72];   // V (modulated) -> proj-out
  __shared__ __align__(16) unsigned short vsT[64*72];  // V^T [ch][key], granule-swizzled
  __shared__ __align__(16) unsigned short wq[192*72];  // w_qkv^T*ln1w -> wproj^T
  __shared__ float rpbs[900];
  __shared__ float bq_s[192];
  __shared__ float rs_tok[64];

  unsigned short* xw = shbuf;
  unsigned short* qs = shbuf + 4608;

  const int tid = threadIdx.x;
  const int lb = ((blockIdx.x & 7) << 10) | (blockIdx.x >> 3);
  const int b = lb >> 10;
  const int win = lb & 1023;
  const int h0 = (win >> 5) << 3;
  const int w0 = (win & 31) << 3;
  const float* xb = x + (size_t)b * 64 * HW;

  const int lane = tid & 63;
  const int w = tid >> 6;         // wave id = head id
  const int fr = lane & 15;       // MFMA row/col-in-tile
  const int fg = lane >> 4;       // MFMA k-group
  const int hb = w * 16;

  for (int i = tid; i < 900; i += 256) rpbs[i] = rpb[i];
  for (int i = tid; i < 192; i += 256) bq_s[i] = bqkv[i];
  for (int i = tid; i < 12288; i += 256) {
    int c = i / 192, o = i - c * 192;
    wq[o*72 + c] = f2bf(wqkv[i] * ln1w[c]);
  }
  for (int i = tid; i < 1024; i += 256) {
    int c = i >> 4, seg = i & 15;
    int row = seg >> 1, half = (seg & 1) * 4;
    float4 v4 = *(const float4*)&xb[(size_t)c * HW + (h0 + row) * WIDTH + w0 + half];
    int p = row * 8 + half;
    xw[(p+0)*72 + c] = f2bf(v4.x);
    xw[(p+1)*72 + c] = f2bf(v4.y);
    xw[(p+2)*72 + c] = f2bf(v4.z);
    xw[(p+3)*72 + c] = f2bf(v4.w);
  }
  __syncthreads();
  // LN stats per token
  {
    int l = tid >> 2, q4 = tid & 3;
    short8v v8a = *(const short8v*)&xw[l*72 + q4*16];
    short8v v8b = *(const short8v*)&xw[l*72 + q4*16 + 8];
    float s = 0.f, s2 = 0.f;
    #pragma unroll
    for (int j = 0; j < 8; ++j) {
      float va = bf2f((unsigned short)v8a[j]), vb = bf2f((unsigned short)v8b[j]);
      s += va + vb; s2 += va * va + vb * vb;
    }
    s += __shfl_down(s, 1); s2 += __shfl_down(s2, 1);
    s += __shfl_down(s, 2); s2 += __shfl_down(s2, 2);
    if (q4 == 0) {
      float mean = s * 0.015625f;
      float var = s2 * 0.015625f - mean * mean;
      rs_tok[l] = rsqrtf(var + 1e-5f);
    }
  }
  __syncthreads();
  // qkv via MFMA
  {
    short8v a[4][2];
    #pragma unroll
    for (int rt = 0; rt < 4; ++rt)
      #pragma unroll
      for (int kh = 0; kh < 2; ++kh)
        a[rt][kh] = *(const short8v*)&xw[(rt*16 + fr)*72 + kh*32 + fg*8];
    #pragma unroll
    for (int part = 0; part < 3; ++part) {
      int ob = part * 64 + hb;
      short8v b0 = *(const short8v*)&wq[(ob + fr)*72 + fg*8];
      short8v b1 = *(const short8v*)&wq[(ob + fr)*72 + 32 + fg*8];
      float bias = bq_s[ob + fr];
      #pragma unroll
      for (int rt = 0; rt < 4; ++rt) {
        f32x4 acc = {0.f, 0.f, 0.f, 0.f};
        acc = __builtin_amdgcn_mfma_f32_16x16x32_bf16(a[rt][0], b0, acc, 0, 0, 0);
        acc = __builtin_amdgcn_mfma_f32_16x16x32_bf16(a[rt][1], b1, acc, 0, 0, 0);
        #pragma unroll
        for (int r = 0; r < 4; ++r) {
          int t = rt*16 + fg*4 + r;
          float val = acc[r] * rs_tok[t] + bias;
          if (part == 0)      qs[t*72 + hb + fr] = f2bf(val * 0.25f);
          else if (part == 1) ks[t*72 + hb + fr] = f2bf(val);
          else                vs[t*72 + hb + fr] = f2bf(val);
        }
      }
    }
  }
  __syncthreads();
  // stage illu -> xw and wproj^T -> wq
  {
    const float* ib = illu + (size_t)b * 64 * HW;
    for (int i = tid; i < 1024; i += 256) {
      int c = i >> 4, seg = i & 15;
      int row = seg >> 1, half = (seg & 1) * 4;
      float4 v4 = *(const float4*)&ib[(size_t)c * HW + (h0 + row) * WIDTH + w0 + half];
      int p = row * 8 + half;
      xw[(p+0)*72 + c] = f2bf(v4.x);
      xw[(p+1)*72 + c] = f2bf(v4.y);
      xw[(p+2)*72 + c] = f2bf(v4.z);
      xw[(p+3)*72 + c] = f2bf(v4.w);
    }
    for (int i = tid; i < 4096; i += 256) {
      int c = i >> 6, o = i & 63;
      wq[o*72 + c] = f2bf(wproj[i]);
    }
  }
  __syncthreads();
  // modulate V and build swizzled V^T
  for (int i = tid; i < 4096; i += 256) {
    int l = i >> 6, c = i & 63;
    unsigned short vb16 = f2bf(bf2f(vs[l*72 + c]) * bf2f(xw[l*72 + c]));
    vs[l*72 + c] = vb16;
    vsT[c*72 + ((((l >> 3) ^ (c & 7)) << 3) | (l & 7))] = vb16;
  }
  __syncthreads();
  // ---- attention via MFMA: S^T = mfma(K, Q); softmax in regs; PV via P-buffer ----
  float inv_s[4];
  {
    short8v zero8 = {0,0,0,0,0,0,0,0};
    short8v kf[4], qf[4];
    #pragma unroll
    for (int t = 0; t < 4; ++t) {
      if (fg < 2) {
        kf[t] = *(const short8v*)&ks[(t*16 + fr)*72 + hb + fg*8];
        qf[t] = *(const short8v*)&qs[(t*16 + fr)*72 + hb + fg*8];
      } else { kf[t] = zero8; qf[t] = zero8; }
    }
    f32x4 st[4][4];
    #pragma unroll
    for (int kt = 0; kt < 4; ++kt)
      #pragma unroll
      for (int qt = 0; qt < 4; ++qt) {
        f32x4 z = {0.f, 0.f, 0.f, 0.f};
        st[kt][qt] = __builtin_amdgcn_mfma_f32_16x16x32_bf16(kf[kt], qf[qt], z, 0, 0, 0);
      }
    // bias + softmax: lane owns q = qt*16+fr, holds keys kt*16+fg*4+r
    float sc[4][16];
    #pragma unroll
    for (int qt = 0; qt < 4; ++qt) {
      int qi = qt*2 + (fr >> 3);
      int qj = fr & 7;
      float mx = -1e30f;
      #pragma unroll
      for (int kt = 0; kt < 4; ++kt) {
        int ki = kt*2 + (fg >> 1);
        int kj0 = (fg & 1) * 4;
        int base = ((qi - ki + 7)*15 + (qj - kj0 + 7))*4 + w;
        #pragma unroll
        for (int r = 0; r < 4; ++r) {
          float v = st[kt][qt][r] + rpbs[base - 4*r];
          sc[qt][kt*4 + r] = v;
          mx = fmaxf(mx, v);
        }
      }
      mx = fmaxf(mx, __shfl_xor(mx, 16));
      mx = fmaxf(mx, __shfl_xor(mx, 32));
      float ss = 0.f;
      #pragma unroll
      for (int j = 0; j < 16; ++j) { float e = __expf(sc[qt][j] - mx); sc[qt][j] = e; ss += e; }
      ss += __shfl_xor(ss, 16);
      ss += __shfl_xor(ss, 32);
      inv_s[qt] = 1.f / ss;
    }
    __syncthreads();  // all waves done reading qs/ks-frags -> shbuf becomes P-buffers
    unsigned short* pb = shbuf + w * 2304;   // [64 q][36] bf16, 32 keys per pass
    f32x4 ot[4];
    #pragma unroll
    for (int nt = 0; nt < 4; ++nt) { f32x4 z = {0.f,0.f,0.f,0.f}; ot[nt] = z; }
    #pragma unroll
    for (int P = 0; P < 2; ++P) {
      #pragma unroll
      for (int qt = 0; qt < 4; ++qt)
        #pragma unroll
        for (int k2 = 0; k2 < 2; ++k2) {
          int kt = 2*P + k2;
          unsigned int lo = (unsigned)f2bf(sc[qt][kt*4+0]) | ((unsigned)f2bf(sc[qt][kt*4+1]) << 16);
          unsigned int hi = (unsigned)f2bf(sc[qt][kt*4+2]) | ((unsigned)f2bf(sc[qt][kt*4+3]) << 16);
          uint2 pk; pk.x = lo; pk.y = hi;
          *(uint2*)&pb[(qt*16 + fr)*36 + k2*16 + fg*4] = pk;
        }
      __syncthreads();  // uniform; orders P-writes before reads
      short8v av = *(const short8v*)&vsT[(hb + fr)*72 + (((P*4 + fg) ^ ((hb + fr) & 7)) << 3)];
      #pragma unroll
      for (int nt = 0; nt < 4; ++nt) {
        short4v p0 = *(const short4v*)&pb[(nt*16 + fr)*36 + fg*8];
        short4v p1 = *(const short4v*)&pb[(nt*16 + fr)*36 + fg*8 + 4];
        short8v bv;
        #pragma unroll
        for (int j = 0; j < 4; ++j) { bv[j] = p0[j]; bv[4+j] = p1[j]; }
        ot[nt] = __builtin_amdgcn_mfma_f32_16x16x32_bf16(av, bv, ot[nt], 0, 0, 0);
      }
      __syncthreads();  // reads done before next P overwrites pb
    }
    // attn-out -> ks[token][hb+d]
    #pragma unroll
    for (int nt = 0; nt < 4; ++nt) {
      float iv = inv_s[nt];
      unsigned int lo = (unsigned)f2bf(ot[nt][0]*iv) | ((unsigned)f2bf(ot[nt][1]*iv) << 16);
      unsigned int hi = (unsigned)f2bf(ot[nt][2]*iv) | ((unsigned)f2bf(ot[nt][3]*iv) << 16);
      uint2 pk; pk.x = lo; pk.y = hi;
      *(uint2*)&ks[(nt*16 + fr)*72 + hb + fg*4] = pk;
    }
  }
  __syncthreads();
  // proj: A = attn-out (ks), B = wproj^T; result -> vs
  {
    short8v a[4][2];
    #pragma unroll
    for (int rt = 0; rt < 4; ++rt)
      #pragma unroll
      for (int kh = 0; kh < 2; ++kh)
        a[rt][kh] = *(const short8v*)&ks[(rt*16 + fr)*72 + kh*32 + fg*8];
    short8v b0 = *(const short8v*)&wq[(hb + fr)*72 + fg*8];
    short8v b1 = *(const short8v*)&wq[(hb + fr)*72 + 32 + fg*8];
    #pragma unroll
    for (int rt = 0; rt < 4; ++rt) {
      f32x4 acc = {0.f, 0.f, 0.f, 0.f};
      acc = __builtin_amdgcn_mfma_f32_16x16x32_bf16(a[rt][0], b0, acc, 0, 0, 0);
      acc = __builtin_amdgcn_mfma_f32_16x16x32_bf16(a[rt][1], b1, acc, 0, 0, 0);
      #pragma unroll
      for (int r = 0; r < 4; ++r)
        vs[(rt*16 + fg*4 + r)*72 + hb + fr] = f2bf(acc[r]);
    }
  }
  __syncthreads();
  // final: residual + bias
  if (use_sp) {
    // bf16 blob [b][win][row][c][px]: fully coalesced 8B/lane stores
    unsigned short* spw = sp + (size_t)(b * 1024 + win) * 4096;
    for (int i = tid; i < 1024; i += 256) {
      int row = i >> 7, rem = i & 127;
      int c = rem >> 1, half = (rem & 1) * 4;
      int p = row * 8 + half;
      size_t gofs = (size_t)c * HW + (h0 + row) * WIDTH + w0 + half;
      float4 xr4 = *(const float4*)&xb[gofs];
      float bp = bproj[c];
      unsigned int lo = (unsigned)f2bf(xr4.x + bp + bf2f(vs[(p+0)*72 + c]))
                      | ((unsigned)f2bf(xr4.y + bp + bf2f(vs[(p+1)*72 + c])) << 16);
      unsigned int hi = (unsigned)f2bf(xr4.z + bp + bf2f(vs[(p+2)*72 + c]))
                      | ((unsigned)f2bf(xr4.w + bp + bf2f(vs[(p+3)*72 + c])) << 16);
      uint2 pk; pk.x = lo; pk.y = hi;
      *(uint2*)&spw[row*512 + c*8 + half] = pk;
    }
  } else {
    for (int i = tid; i < 1024; i += 256) {
      int o = i >> 4, seg = i & 15;
      int row = seg >> 1, half = (seg & 1) * 4;
      int p = row * 8 + half;
      size_t gofs = (size_t)o * HW + (h0 + row) * WIDTH + w0 + half;
      float4 xr4 = *(const float4*)&xb[gofs];
      float bp = bproj[o];
      float4 r;
      r.x = xr4.x + bp + bf2f(vs[(p+0)*72 + o]);
      r.y = xr4.y + bp + bf2f(vs[(p+1)*72 + o]);
      r.z = xr4.z + bp + bf2f(vs[(p+2)*72 + o]);
      r.w = xr4.w + bp + bf2f(vs[(p+3)*72 + o]);
      *(float4*)&out[(size_t)b * 64 * HW + gofs] = r;
    }
  }
}

// ---------------- Channel branch producer (unchanged, passing) ----------------
__global__ __launch_bounds__(256, 2) void k_chan_qkv(
    const float* __restrict__ x, const float* __restrict__ illu,
    const float* __restrict__ ln2w, const float* __restrict__ w1,
    const float* __restrict__ wdw,
    unsigned short* __restrict__ vm, float* __restrict__ Gp,
    float* __restrict__ Nqp, float* __restrict__ Nkp)
{
  __shared__ __align__(16) unsigned short xh[336*64];
  __shared__ __align__(16) unsigned short tb[16*344];
  __shared__ __align__(16) unsigned short qc[16*256];
  __shared__ __align__(16) unsigned short kc[16*256];
  __shared__ float rsp[324];
  __shared__ unsigned short wdws[1728];

  const int tid = threadIdx.x;
  const int blk = blockIdx.x;
  const int b = blk >> 8;
  const int tile = blk & 255;
  const int ty0 = (tile >> 4) << 4, tx0 = (tile & 15) << 4;
  const float* xb = x + (size_t)b * 64 * HW;

  for (int i = tid; i < 64 * 324; i += 256) {
    int c = i / 324, p = i - c * 324;
    int hy = p / 18, hx = p - hy * 18;
    int gy = ty0 + hy - 1, gx = tx0 + hx - 1;
    float v = 0.f;
    if (gy >= 0 && gy < 256 && gx >= 0 && gx < 256)
      v = xb[(size_t)c * HW + gy * WIDTH + gx];
    xh[XH_IDX(p, c >> 3) + (c & 7)] = f2bf(v);
  }
  for (int i = tid; i < 12 * 64; i += 256) {
    int p = 324 + (i >> 6), c = i & 63;
    xh[XH_IDX(p, c >> 3) + (c & 7)] = 0;
  }
  for (int i = tid; i < 1728; i += 256) wdws[i] = f2bf(wdw[i]);
  __syncthreads();
  for (int p = tid; p < 324; p += 256) {
    float s = 0.f, s2 = 0.f;
    #pragma unroll
    for (int g = 0; g < 8; ++g) {
      short8v v8 = *(const short8v*)&xh[XH_IDX(p, g)];
      #pragma unroll
      for (int j = 0; j < 8; ++j) { float v = bf2f((unsigned short)v8[j]); s += v; s2 += v * v; }
    }
    float mean = s * 0.015625f;
    float var = s2 * 0.015625f - mean * mean;
    rsp[p] = rsqrtf(var + 1e-5f);
  }
  __syncthreads();

  const int lane = tid & 63;
  const int wid = tid >> 6;
  const int fcol = lane & 15;
  const int fk = lane >> 4;

  auto gemm_chunk = [&](int wbase) {
    short8v bf[2];
    const float* wr = w1 + (size_t)(wbase + fcol) * 64;
    #pragma unroll
    for (int s = 0; s < 2; ++s) {
      int cs = fk * 8 + s * 32;
      #pragma unroll
      for (int j = 0; j < 8; ++j)
        bf[s][j] = (short)f2bf(wr[cs + j] * ln2w[cs + j]);
    }
    for (int t = wid; t < 21; t += 4) {
      int ar = t * 16 + fcol;
      short8v a0 = *(const short8v*)&xh[XH_IDX(ar, fk)];
      short8v a1 = *(const short8v*)&xh[XH_IDX(ar, fk + 4)];
      f32x4 acc = {0.f, 0.f, 0.f, 0.f};
      acc = __builtin_amdgcn_mfma_f32_16x16x32_bf16(a0, bf[0], acc, 0, 0, 0);
      acc = __builtin_amdgcn_mfma_f32_16x16x32_bf16(a1, bf[1], acc, 0, 0, 0);
      #pragma unroll
      for (int r = 0; r < 4; ++r) {
        int px = t * 16 + fk * 4 + r;
        if (px < 324) tb[fcol * 344 + px] = f2bf(acc[r] * rsp[px]);
      }
    }
  };

  float dout[16];
  auto dw_chunk = [&](int wbase) {
    int py = tid >> 4, px = tid & 15;
    #pragma unroll
    for (int oc = 0; oc < 16; ++oc) {
      const unsigned short* w9 = &wdws[(wbase + oc) * 9];
      const unsigned short* tbr = &tb[oc * 344];
      float a = 0.f;
      #pragma unroll
      for (int ky = 0; ky < 3; ++ky) {
        int rb = (py + ky) * 18 + px;
        a += bf2f(w9[ky*3+0]) * bf2f(tbr[rb]);
        a += bf2f(w9[ky*3+1]) * bf2f(tbr[rb + 1]);
        a += bf2f(w9[ky*3+2]) * bf2f(tbr[rb + 2]);
      }
      dout[oc] = a;
    }
  };

  for (int n = 0; n < 4; ++n) {
    gemm_chunk(16 * n);
    __syncthreads();
    dw_chunk(16 * n);
    #pragma unroll
    for (int oc = 0; oc < 16; ++oc) qc[QC_IDX(oc, tid)] = f2bf(dout[oc]);
    __syncthreads();
    {
      int ch = tid >> 4, seg = tid & 15;
      float s = 0.f;
      #pragma unroll
      for (int j = 0; j < 16; ++j) { float v = bf2f(qc[QC_IDX(ch, seg * 16 + j)]); s += v * v; }
      s += __shfl_xor(s, 1); s += __shfl_xor(s, 2); s += __shfl_xor(s, 4); s += __shfl_xor(s, 8);
      if (seg == 0) Nqp[(size_t)blk * 64 + n * 16 + ch] = s;
    }
    gemm_chunk(64 + 16 * n);
    __syncthreads();
    dw_chunk(64 + 16 * n);
    #pragma unroll
    for (int oc = 0; oc < 16; ++oc) kc[QC_IDX(oc, tid)] = f2bf(dout[oc]);
    __syncthreads();
    {
      int ch = tid >> 4, seg = tid & 15;
      float s = 0.f;
      #pragma unroll
      for (int j = 0; j < 16; ++j) { float v = bf2f(kc[QC_IDX(ch, seg * 16 + j)]); s += v * v; }
      s += __shfl_xor(s, 1); s += __shfl_xor(s, 2); s += __shfl_xor(s, 4); s += __shfl_xor(s, 8);
      if (seg == 0) Nkp[(size_t)blk * 64 + n * 16 + ch] = s;
    }
    if (wid == 0) {
      f32x4 g = {0.f, 0.f, 0.f, 0.f};
      #pragma unroll
      for (int s = 0; s < 8; ++s) {
        int G = fk + 4 * s;
        short8v aq = *(const short8v*)&qc[QCG_IDX(fcol, G)];
        short8v bk = *(const short8v*)&kc[QCG_IDX(fcol, G)];
        g = __builtin_amdgcn_mfma_f32_16x16x32_bf16(aq, bk, g, 0, 0, 0);
      }
      float* gp = Gp + ((size_t)blk * 4 + n) * 256;
      #pragma unroll
      for (int r = 0; r < 4; ++r) gp[(fk * 4 + r) * 16 + fcol] = g[r];
    }
  }
  const float* ib = illu + (size_t)b * 64 * HW;
  for (int j = 0; j < 4; ++j) {
    gemm_chunk(128 + 16 * j);
    __syncthreads();
    dw_chunk(128 + 16 * j);
    int gy = ty0 + (tid >> 4), gx = tx0 + (tid & 15);
    size_t ppos = (size_t)gy * WIDTH + gx;
    #pragma unroll
    for (int oc = 0; oc < 16; ++oc) {
      int vc = 16 * j + oc;
      float iv = ib[(size_t)vc * HW + ppos];
      vm[((size_t)b * 64 + vc) * HW + ppos] = f2bf(dout[oc] * iv);
    }
    __syncthreads();
  }
}

// ---------------- two-stage reduction -> softmax -> fold w_out into M ----------------
__global__ __launch_bounds__(256) void k_reduce1(
    const float* __restrict__ Gp, const float* __restrict__ Nqp, const float* __restrict__ Nkp,
    float* __restrict__ G2, float* __restrict__ Nq2, float* __restrict__ Nk2)
{
  const int blk = blockIdx.x;
  const int b = blk >> 5, g = blk & 31;
  const int tid = threadIdx.x;
  float ga[4] = {0.f, 0.f, 0.f, 0.f};
  for (int t = 0; t < 8; ++t) {
    const float* src = Gp + ((size_t)(b * 256 + g * 8 + t)) * 1024;
    #pragma unroll
    for (int j = 0; j < 4; ++j) ga[j] += src[tid + j * 256];
  }
  float* dst = G2 + ((size_t)(b * 32 + g)) * 1024;
  #pragma unroll
  for (int j = 0; j < 4; ++j) dst[tid + j * 256] = ga[j];
  if (tid < 128) {
    int ch = tid & 63; bool isq = tid < 64;
    const float* np = isq ? Nqp : Nkp;
    float s = 0.f;
    for (int t = 0; t < 8; ++t) s += np[((size_t)(b * 256 + g * 8 + t)) * 64 + ch];
    (isq ? Nq2 : Nk2)[(size_t)(b * 32 + g) * 64 + ch] = s;
  }
}

__global__ __launch_bounds__(256) void k_reduce2(
    const float* __restrict__ G2, const float* __restrict__ Nq2, const float* __restrict__ Nk2,
    const float* __restrict__ temp, const float* __restrict__ wout, float* __restrict__ M)
{
  __shared__ float Gs[1024];
  __shared__ float As[4][16][17];
  __shared__ float nq[64], nk[64];
  const int b = blockIdx.x;
  const int tid = threadIdx.x;
  float ga[4] = {0.f, 0.f, 0.f, 0.f};
  for (int g = 0; g < 32; ++g) {
    const float* src = G2 + ((size_t)(b * 32 + g)) * 1024;
    #pragma unroll
    for (int j = 0; j < 4; ++j) ga[j] += src[tid + j * 256];
  }
  #pragma unroll
  for (int j = 0; j < 4; ++j) Gs[tid + j * 256] = ga[j];
  if (tid < 128) {
    int ch = tid & 63; bool isq = tid < 64;
    const float* n2 = isq ? Nq2 : Nk2;
    float s = 0.f;
    for (int g = 0; g < 32; ++g) s += n2[(size_t)(b * 32 + g) * 64 + ch];
    float r = fmaxf(sqrtf(s), 1e-12f);
    (isq ? nq : nk)[ch] = r;
  }
  __syncthreads();
  if (tid < 64) {
    int n = tid >> 4, d = tid & 15;
    float tv = temp[n];
    float row[16]; float mx = -1e30f;
    #pragma unroll
    for (int e = 0; e < 16; ++e) {
      float v = Gs[n * 256 + d * 16 + e] / (nq[n * 16 + d] * nk[n * 16 + e]) * tv;
      row[e] = v; mx = fmaxf(mx, v);
    }
    float s = 0.f;
    #pragma unroll
    for (int e = 0; e < 16; ++e) { float ev = __expf(row[e] - mx); row[e] = ev; s += ev; }
    float inv = 1.f / s;
    #pragma unroll
    for (int e = 0; e < 16; ++e) As[n][d][e] = row[e] * inv;
  }
  __syncthreads();
  float* Mb = M + (size_t)b * 4096;
  for (int i = tid; i < 4096; i += 256) {
    int o = i >> 6, cp = i & 63;
    int n = cp >> 4, e = cp & 15;
    float a = 0.f;
    #pragma unroll
    for (int d = 0; d < 16; ++d) a += wout[o * 64 + n * 16 + d] * As[n][d][e];
    Mb[i] = a;
  }
}

// ---------------- apply M to vm; combine with spatial blob; write out ----------------
__global__ __launch_bounds__(256, 3) void k_mdta_out(
    const unsigned short* __restrict__ vm, const float* __restrict__ M,
    const unsigned short* __restrict__ sp, int use_sp,
    float* __restrict__ out)
{
  __shared__ __align__(16) float Ml[4096];
  __shared__ __align__(16) unsigned short spl[64 * 264];
  const int blk = blockIdx.x;
  const int b = blk >> 8;
  const int y = blk & 255;      // full image row; pixels y*256 .. y*256+255
  const int tid = threadIdx.x;

  const float* Mb = M + (size_t)b * 4096;
  for (int i = tid; i < 4096; i += 256) Ml[i] = Mb[i];
  if (use_sp) {
    int wy = y >> 3, py = y & 7;
    const unsigned short* spb = sp + ((((size_t)b * 1024 + wy * 32) * 8) + py) * 512;
    for (int k = 0; k < 8; ++k) {
      int i3 = k * 256 + tid;
      int o = i3 & 63, wx = i3 >> 6;
      short8v v8 = *(const short8v*)&spb[(size_t)wx * 4096 + o * 8];
      *(short8v*)&spl[o * 264 + wx * 8] = v8;
    }
  }
  __syncthreads();
  float xcol[64];
  const unsigned short* vb = vm + (size_t)b * 64 * HW + y * 256 + tid;
  #pragma unroll
  for (int c = 0; c < 64; ++c) xcol[c] = bf2f(vb[(size_t)c * HW]);
  float* ob = out + (size_t)b * 64 * HW + y * 256 + tid;
  for (int o = 0; o < 64; ++o) {
    const float4* mr = (const float4*)&Ml[o * 64];
    float acc = 0.f;
    #pragma unroll
    for (int g = 0; g < 16; ++g) {
      float4 m4 = mr[g];
      acc += m4.x * xcol[g*4] + m4.y * xcol[g*4+1] + m4.z * xcol[g*4+2] + m4.w * xcol[g*4+3];
    }
    if (use_sp) ob[(size_t)o * HW] = bf2f(spl[o * 264 + tid]) + acc;
    else        ob[(size_t)o * HW] += acc;
  }
}

extern "C" void kernel_launch(void* const* d_in, const int* in_sizes, int n_in,
                              void* d_out, int out_size, void* d_ws, size_t ws_size,
                              hipStream_t stream) {
  const float* x     = (const float*)d_in[0];
  const float* illu  = (const float*)d_in[1];
  const float* ln1w  = (const float*)d_in[2];
  const float* ln2w  = (const float*)d_in[3];
  const float* wqkv  = (const float*)d_in[4];
  const float* bqkv  = (const float*)d_in[5];
  const float* rpb   = (const float*)d_in[6];
  const float* wproj = (const float*)d_in[7];
  const float* bproj = (const float*)d_in[8];
  const float* temp  = (const float*)d_in[9];
  const float* w1    = (const float*)d_in[10];
  const float* wdw   = (const float*)d_in[11];
  const float* wout  = (const float*)d_in[12];
  float* out = (float*)d_out;

  char* ws = (char*)d_ws;
  unsigned short* vm = (unsigned short*)ws;            // 67,108,864 B
  float* Gp  = (float*)(ws + 67108864);                //  8,388,608 B
  float* Nqp = (float*)(ws + 75497472);                //    524,288 B
  float* Nkp = (float*)(ws + 76021760);                //    524,288 B
  float* G2  = (float*)(ws + 76546048);                //  1,048,576 B
  float* Nq2 = (float*)(ws + 77594624);                //     65,536 B
  float* Nk2 = (float*)(ws + 77660160);                //     65,536 B
  float* M   = (float*)(ws + 77725696);                //    131,072 B
  unsigned short* sp = (unsigned short*)(ws + SP_OFF); // 67,108,864 B (if available)
  int use_sp = (ws_size >= SP_OFF + 67108864ull) ? 1 : 0;

  k_spatial<<<8192, 256, 0, stream>>>(x, illu, ln1w, wqkv, bqkv, rpb, wproj, bproj,
                                      out, sp, use_sp);
  k_chan_qkv<<<2048, 256, 0, stream>>>(x, illu, ln2w, w1, wdw, vm, Gp, Nqp, Nkp);
  k_reduce1<<<256, 256, 0, stream>>>(Gp, Nqp, Nkp, G2, Nq2, Nk2);
  k_reduce2<<<8, 256, 0, stream>>>(G2, Nq2, Nk2, temp, wout, M);
  k_mdta_out<<<2048, 256, 0, stream>>>(vm, M, sp, use_sp, out);
}

// Round 8
// 789.177 us; speedup vs baseline: 5.7982x; 1.0330x over previous
//
#include <hip/hip_runtime.h>
#include <hip/hip_bf16.h>

#define HW 65536
#define WIDTH 256
#define SP_OFF 77856768ull   // ws offset of spatial-out blob (67,108,864 B bf16)

typedef __attribute__((ext_vector_type(8))) short short8v;
typedef __attribute__((ext_vector_type(4))) short short4v;
typedef __attribute__((ext_vector_type(4))) float f32x4;

__device__ inline float bf2f(unsigned short u) {
  unsigned int i = ((unsigned int)u) << 16;
  float f; __builtin_memcpy(&f, &i, 4); return f;
}
__device__ inline unsigned short f2bf(float x) {
  __hip_bfloat16 h = __float2bfloat16(x);
  unsigned short u; __builtin_memcpy(&u, &h, 2); return u;
}

// swizzled LDS indexers for k_chan_qkv (granule = 8 bf16 = 16B)
#define XH_IDX(p, g) ((p)*64 + ((((g) ^ ((p)&7)))<<3))
#define QC_IDX(ch, px) ((ch)*256 + ((((px)>>3) ^ ((ch)&7))<<3) + ((px)&7))
#define QCG_IDX(ch, G) ((ch)*256 + ((((G) ^ ((ch)&7)))<<3))

// ---------------- Spatial window-attention branch (unchanged, passing) ----------------
__global__ __launch_bounds__(256, 2) void k_spatial(
    const float* __restrict__ x, const float* __restrict__ illu,
    const float* __restrict__ ln1w, const float* __restrict__ wqkv,
    const float* __restrict__ bqkv, const float* __restrict__ rpb,
    const float* __restrict__ wproj, const float* __restrict__ bproj,
    float* __restrict__ out, unsigned short* __restrict__ sp, int use_sp)
{
  __shared__ __align__(16) unsigned short shbuf[9216]; // xw | qs, later 4x P-buffers
  __shared__ __align__(16) unsigned short ks[64*72];   // K -> attn-out
  __shared__ __align__(16) unsigned short vs[64*72];   // V (modulated) -> proj-out
  __shared__ __align__(16) unsigned short vsT[64*72];  // V^T [ch][key], granule-swizzled
  __shared__ __align__(16) unsigned short wq[192*72];  // w_qkv^T*ln1w -> wproj^T
  __shared__ float rpbs[900];
  __shared__ float bq_s[192];
  __shared__ float rs_tok[64];

  unsigned short* xw = shbuf;
  unsigned short* qs = shbuf + 4608;

  const int tid = threadIdx.x;
  const int lb = ((blockIdx.x & 7) << 10) | (blockIdx.x >> 3);
  const int b = lb >> 10;
  const int win = lb & 1023;
  const int h0 = (win >> 5) << 3;
  const int w0 = (win & 31) << 3;
  const float* xb = x + (size_t)b * 64 * HW;

  const int lane = tid & 63;
  const int w = tid >> 6;
  const int fr = lane & 15;
  const int fg = lane >> 4;
  const int hb = w * 16;

  for (int i = tid; i < 900; i += 256) rpbs[i] = rpb[i];
  for (int i = tid; i < 192; i += 256) bq_s[i] = bqkv[i];
  for (int i = tid; i < 12288; i += 256) {
    int c = i / 192, o = i - c * 192;
    wq[o*72 + c] = f2bf(wqkv[i] * ln1w[c]);
  }
  for (int i = tid; i < 1024; i += 256) {
    int c = i >> 4, seg = i & 15;
    int row = seg >> 1, half = (seg & 1) * 4;
    float4 v4 = *(const float4*)&xb[(size_t)c * HW + (h0 + row) * WIDTH + w0 + half];
    int p = row * 8 + half;
    xw[(p+0)*72 + c] = f2bf(v4.x);
    xw[(p+1)*72 + c] = f2bf(v4.y);
    xw[(p+2)*72 + c] = f2bf(v4.z);
    xw[(p+3)*72 + c] = f2bf(v4.w);
  }
  __syncthreads();
  {
    int l = tid >> 2, q4 = tid & 3;
    short8v v8a = *(const short8v*)&xw[l*72 + q4*16];
    short8v v8b = *(const short8v*)&xw[l*72 + q4*16 + 8];
    float s = 0.f, s2 = 0.f;
    #pragma unroll
    for (int j = 0; j < 8; ++j) {
      float va = bf2f((unsigned short)v8a[j]), vb = bf2f((unsigned short)v8b[j]);
      s += va + vb; s2 += va * va + vb * vb;
    }
    s += __shfl_down(s, 1); s2 += __shfl_down(s2, 1);
    s += __shfl_down(s, 2); s2 += __shfl_down(s2, 2);
    if (q4 == 0) {
      float mean = s * 0.015625f;
      float var = s2 * 0.015625f - mean * mean;
      rs_tok[l] = rsqrtf(var + 1e-5f);
    }
  }
  __syncthreads();
  {
    short8v a[4][2];
    #pragma unroll
    for (int rt = 0; rt < 4; ++rt)
      #pragma unroll
      for (int kh = 0; kh < 2; ++kh)
        a[rt][kh] = *(const short8v*)&xw[(rt*16 + fr)*72 + kh*32 + fg*8];
    #pragma unroll
    for (int part = 0; part < 3; ++part) {
      int ob = part * 64 + hb;
      short8v b0 = *(const short8v*)&wq[(ob + fr)*72 + fg*8];
      short8v b1 = *(const short8v*)&wq[(ob + fr)*72 + 32 + fg*8];
      float bias = bq_s[ob + fr];
      #pragma unroll
      for (int rt = 0; rt < 4; ++rt) {
        f32x4 acc = {0.f, 0.f, 0.f, 0.f};
        acc = __builtin_amdgcn_mfma_f32_16x16x32_bf16(a[rt][0], b0, acc, 0, 0, 0);
        acc = __builtin_amdgcn_mfma_f32_16x16x32_bf16(a[rt][1], b1, acc, 0, 0, 0);
        #pragma unroll
        for (int r = 0; r < 4; ++r) {
          int t = rt*16 + fg*4 + r;
          float val = acc[r] * rs_tok[t] + bias;
          if (part == 0)      qs[t*72 + hb + fr] = f2bf(val * 0.25f);
          else if (part == 1) ks[t*72 + hb + fr] = f2bf(val);
          else                vs[t*72 + hb + fr] = f2bf(val);
        }
      }
    }
  }
  __syncthreads();
  {
    const float* ib = illu + (size_t)b * 64 * HW;
    for (int i = tid; i < 1024; i += 256) {
      int c = i >> 4, seg = i & 15;
      int row = seg >> 1, half = (seg & 1) * 4;
      float4 v4 = *(const float4*)&ib[(size_t)c * HW + (h0 + row) * WIDTH + w0 + half];
      int p = row * 8 + half;
      xw[(p+0)*72 + c] = f2bf(v4.x);
      xw[(p+1)*72 + c] = f2bf(v4.y);
      xw[(p+2)*72 + c] = f2bf(v4.z);
      xw[(p+3)*72 + c] = f2bf(v4.w);
    }
    for (int i = tid; i < 4096; i += 256) {
      int c = i >> 6, o = i & 63;
      wq[o*72 + c] = f2bf(wproj[i]);
    }
  }
  __syncthreads();
  for (int i = tid; i < 4096; i += 256) {
    int l = i >> 6, c = i & 63;
    unsigned short vb16 = f2bf(bf2f(vs[l*72 + c]) * bf2f(xw[l*72 + c]));
    vs[l*72 + c] = vb16;
    vsT[c*72 + ((((l >> 3) ^ (c & 7)) << 3) | (l & 7))] = vb16;
  }
  __syncthreads();
  float inv_s[4];
  {
    short8v zero8 = {0,0,0,0,0,0,0,0};
    short8v kf[4], qf[4];
    #pragma unroll
    for (int t = 0; t < 4; ++t) {
      if (fg < 2) {
        kf[t] = *(const short8v*)&ks[(t*16 + fr)*72 + hb + fg*8];
        qf[t] = *(const short8v*)&qs[(t*16 + fr)*72 + hb + fg*8];
      } else { kf[t] = zero8; qf[t] = zero8; }
    }
    f32x4 st[4][4];
    #pragma unroll
    for (int kt = 0; kt < 4; ++kt)
      #pragma unroll
      for (int qt = 0; qt < 4; ++qt) {
        f32x4 z = {0.f, 0.f, 0.f, 0.f};
        st[kt][qt] = __builtin_amdgcn_mfma_f32_16x16x32_bf16(kf[kt], qf[qt], z, 0, 0, 0);
      }
    float sc[4][16];
    #pragma unroll
    for (int qt = 0; qt < 4; ++qt) {
      int qi = qt*2 + (fr >> 3);
      int qj = fr & 7;
      float mx = -1e30f;
      #pragma unroll
      for (int kt = 0; kt < 4; ++kt) {
        int ki = kt*2 + (fg >> 1);
        int kj0 = (fg & 1) * 4;
        int base = ((qi - ki + 7)*15 + (qj - kj0 + 7))*4 + w;
        #pragma unroll
        for (int r = 0; r < 4; ++r) {
          float v = st[kt][qt][r] + rpbs[base - 4*r];
          sc[qt][kt*4 + r] = v;
          mx = fmaxf(mx, v);
        }
      }
      mx = fmaxf(mx, __shfl_xor(mx, 16));
      mx = fmaxf(mx, __shfl_xor(mx, 32));
      float ss = 0.f;
      #pragma unroll
      for (int j = 0; j < 16; ++j) { float e = __expf(sc[qt][j] - mx); sc[qt][j] = e; ss += e; }
      ss += __shfl_xor(ss, 16);
      ss += __shfl_xor(ss, 32);
      inv_s[qt] = 1.f / ss;
    }
    __syncthreads();
    unsigned short* pb = shbuf + w * 2304;
    f32x4 ot[4];
    #pragma unroll
    for (int nt = 0; nt < 4; ++nt) { f32x4 z = {0.f,0.f,0.f,0.f}; ot[nt] = z; }
    #pragma unroll
    for (int P = 0; P < 2; ++P) {
      #pragma unroll
      for (int qt = 0; qt < 4; ++qt)
        #pragma unroll
        for (int k2 = 0; k2 < 2; ++k2) {
          int kt = 2*P + k2;
          unsigned int lo = (unsigned)f2bf(sc[qt][kt*4+0]) | ((unsigned)f2bf(sc[qt][kt*4+1]) << 16);
          unsigned int hi = (unsigned)f2bf(sc[qt][kt*4+2]) | ((unsigned)f2bf(sc[qt][kt*4+3]) << 16);
          uint2 pk; pk.x = lo; pk.y = hi;
          *(uint2*)&pb[(qt*16 + fr)*36 + k2*16 + fg*4] = pk;
        }
      __syncthreads();
      short8v av = *(const short8v*)&vsT[(hb + fr)*72 + (((P*4 + fg) ^ ((hb + fr) & 7)) << 3)];
      #pragma unroll
      for (int nt = 0; nt < 4; ++nt) {
        short4v p0 = *(const short4v*)&pb[(nt*16 + fr)*36 + fg*8];
        short4v p1 = *(const short4v*)&pb[(nt*16 + fr)*36 + fg*8 + 4];
        short8v bv;
        #pragma unroll
        for (int j = 0; j < 4; ++j) { bv[j] = p0[j]; bv[4+j] = p1[j]; }
        ot[nt] = __builtin_amdgcn_mfma_f32_16x16x32_bf16(av, bv, ot[nt], 0, 0, 0);
      }
      __syncthreads();
    }
    #pragma unroll
    for (int nt = 0; nt < 4; ++nt) {
      float iv = inv_s[nt];
      unsigned int lo = (unsigned)f2bf(ot[nt][0]*iv) | ((unsigned)f2bf(ot[nt][1]*iv) << 16);
      unsigned int hi = (unsigned)f2bf(ot[nt][2]*iv) | ((unsigned)f2bf(ot[nt][3]*iv) << 16);
      uint2 pk; pk.x = lo; pk.y = hi;
      *(uint2*)&ks[(nt*16 + fr)*72 + hb + fg*4] = pk;
    }
  }
  __syncthreads();
  {
    short8v a[4][2];
    #pragma unroll
    for (int rt = 0; rt < 4; ++rt)
      #pragma unroll
      for (int kh = 0; kh < 2; ++kh)
        a[rt][kh] = *(const short8v*)&ks[(rt*16 + fr)*72 + kh*32 + fg*8];
    short8v b0 = *(const short8v*)&wq[(hb + fr)*72 + fg*8];
    short8v b1 = *(const short8v*)&wq[(hb + fr)*72 + 32 + fg*8];
    #pragma unroll
    for (int rt = 0; rt < 4; ++rt) {
      f32x4 acc = {0.f, 0.f, 0.f, 0.f};
      acc = __builtin_amdgcn_mfma_f32_16x16x32_bf16(a[rt][0], b0, acc, 0, 0, 0);
      acc = __builtin_amdgcn_mfma_f32_16x16x32_bf16(a[rt][1], b1, acc, 0, 0, 0);
      #pragma unroll
      for (int r = 0; r < 4; ++r)
        vs[(rt*16 + fg*4 + r)*72 + hb + fr] = f2bf(acc[r]);
    }
  }
  __syncthreads();
  if (use_sp) {
    unsigned short* spw = sp + (size_t)(b * 1024 + win) * 4096;
    for (int i = tid; i < 1024; i += 256) {
      int row = i >> 7, rem = i & 127;
      int c = rem >> 1, half = (rem & 1) * 4;
      int p = row * 8 + half;
      size_t gofs = (size_t)c * HW + (h0 + row) * WIDTH + w0 + half;
      float4 xr4 = *(const float4*)&xb[gofs];
      float bp = bproj[c];
      unsigned int lo = (unsigned)f2bf(xr4.x + bp + bf2f(vs[(p+0)*72 + c]))
                      | ((unsigned)f2bf(xr4.y + bp + bf2f(vs[(p+1)*72 + c])) << 16);
      unsigned int hi = (unsigned)f2bf(xr4.z + bp + bf2f(vs[(p+2)*72 + c]))
                      | ((unsigned)f2bf(xr4.w + bp + bf2f(vs[(p+3)*72 + c])) << 16);
      uint2 pk; pk.x = lo; pk.y = hi;
      *(uint2*)&spw[row*512 + c*8 + half] = pk;
    }
  } else {
    for (int i = tid; i < 1024; i += 256) {
      int o = i >> 4, seg = i & 15;
      int row = seg >> 1, half = (seg & 1) * 4;
      int p = row * 8 + half;
      size_t gofs = (size_t)o * HW + (h0 + row) * WIDTH + w0 + half;
      float4 xr4 = *(const float4*)&xb[gofs];
      float bp = bproj[o];
      float4 r;
      r.x = xr4.x + bp + bf2f(vs[(p+0)*72 + o]);
      r.y = xr4.y + bp + bf2f(vs[(p+1)*72 + o]);
      r.z = xr4.z + bp + bf2f(vs[(p+2)*72 + o]);
      r.w = xr4.w + bp + bf2f(vs[(p+3)*72 + o]);
      *(float4*)&out[(size_t)b * 64 * HW + gofs] = r;
    }
  }
}

// ---------------- Channel branch producer: LDS-lean depthwise ----------------
// tb stored as [oc][18 rows x 20 cols] (stride-4-aligned rows) so the dw pass
// reads each (oc,ky) 6-tap segment as ds_read_b64 + ds_read_b32.
// dw weights read from global (wave-uniform -> scalar/L1-broadcast).
__global__ __launch_bounds__(256, 2) void k_chan_qkv(
    const float* __restrict__ x, const float* __restrict__ illu,
    const float* __restrict__ ln2w, const float* __restrict__ w1,
    const float* __restrict__ wdw,
    unsigned short* __restrict__ vm, float* __restrict__ Gp,
    float* __restrict__ Nqp, float* __restrict__ Nkp)
{
  __shared__ __align__(16) unsigned short xh[336*64];  // raw x halo, swizzled; rows 324+ zero
  __shared__ __align__(16) unsigned short tb[16*360];  // 1x1 chunk over halo, [oc][hy*20+hx]
  __shared__ __align__(16) unsigned short qc[16*256];
  __shared__ __align__(16) unsigned short kc[16*256];
  __shared__ float rsp[324];

  const int tid = threadIdx.x;
  const int blk = blockIdx.x;
  const int b = blk >> 8;
  const int tile = blk & 255;
  const int ty0 = (tile >> 4) << 4, tx0 = (tile & 15) << 4;
  const float* xb = x + (size_t)b * 64 * HW;

  for (int i = tid; i < 64 * 324; i += 256) {
    int c = i / 324, p = i - c * 324;
    int hy = p / 18, hx = p - hy * 18;
    int gy = ty0 + hy - 1, gx = tx0 + hx - 1;
    float v = 0.f;
    if (gy >= 0 && gy < 256 && gx >= 0 && gx < 256)
      v = xb[(size_t)c * HW + gy * WIDTH + gx];
    xh[XH_IDX(p, c >> 3) + (c & 7)] = f2bf(v);
  }
  for (int i = tid; i < 12 * 64; i += 256) {
    int p = 324 + (i >> 6), c = i & 63;
    xh[XH_IDX(p, c >> 3) + (c & 7)] = 0;
  }
  __syncthreads();
  for (int p = tid; p < 324; p += 256) {
    float s = 0.f, s2 = 0.f;
    #pragma unroll
    for (int g = 0; g < 8; ++g) {
      short8v v8 = *(const short8v*)&xh[XH_IDX(p, g)];
      #pragma unroll
      for (int j = 0; j < 8; ++j) { float v = bf2f((unsigned short)v8[j]); s += v; s2 += v * v; }
    }
    float mean = s * 0.015625f;
    float var = s2 * 0.015625f - mean * mean;
    rsp[p] = rsqrtf(var + 1e-5f);
  }
  __syncthreads();

  const int lane = tid & 63;
  const int wid = tid >> 6;
  const int fcol = lane & 15;
  const int fk = lane >> 4;
  // dw-pass thread mapping: wave = 4-oc group, then 16 rows x 4 px-groups
  const int dpy = (tid >> 2) & 15;
  const int dg = tid & 3;

  auto gemm_chunk = [&](int wbase) {
    short8v bf[2];
    const float* wr = w1 + (size_t)(wbase + fcol) * 64;
    #pragma unroll
    for (int s = 0; s < 2; ++s) {
      int cs = fk * 8 + s * 32;
      #pragma unroll
      for (int j = 0; j < 8; ++j)
        bf[s][j] = (short)f2bf(wr[cs + j] * ln2w[cs + j]);
    }
    for (int t = wid; t < 21; t += 4) {
      int ar = t * 16 + fcol;
      short8v a0 = *(const short8v*)&xh[XH_IDX(ar, fk)];
      short8v a1 = *(const short8v*)&xh[XH_IDX(ar, fk + 4)];
      f32x4 acc = {0.f, 0.f, 0.f, 0.f};
      acc = __builtin_amdgcn_mfma_f32_16x16x32_bf16(a0, bf[0], acc, 0, 0, 0);
      acc = __builtin_amdgcn_mfma_f32_16x16x32_bf16(a1, bf[1], acc, 0, 0, 0);
      #pragma unroll
      for (int r = 0; r < 4; ++r) {
        int px = t * 16 + fk * 4 + r;
        if (px < 324) {
          int hy = px / 18, hx = px - hy * 18;
          tb[fcol * 360 + hy * 20 + hx] = f2bf(acc[r] * rsp[px]);
        }
      }
    }
  };

  float dout4[4][4];   // [oc4][px-in-group]
  auto dw_chunk = [&](int wbase) {
    #pragma unroll
    for (int oc4 = 0; oc4 < 4; ++oc4) {
      int oc = wid * 4 + oc4;
      const float* w9 = wdw + (size_t)(wbase + oc) * 9;
      float wk[9];
      #pragma unroll
      for (int t = 0; t < 9; ++t) wk[t] = w9[t];
      float a0 = 0.f, a1 = 0.f, a2 = 0.f, a3 = 0.f;
      #pragma unroll
      for (int ky = 0; ky < 3; ++ky) {
        int base = oc * 360 + (dpy + ky) * 20 + dg * 4;
        short4v t4 = *(const short4v*)&tb[base];
        unsigned int t2 = *(const unsigned int*)&tb[base + 4];
        float e0 = bf2f((unsigned short)t4[0]);
        float e1 = bf2f((unsigned short)t4[1]);
        float e2 = bf2f((unsigned short)t4[2]);
        float e3 = bf2f((unsigned short)t4[3]);
        float e4 = bf2f((unsigned short)(t2 & 0xffff));
        float e5 = bf2f((unsigned short)(t2 >> 16));
        float k0 = wk[ky*3+0], k1 = wk[ky*3+1], k2 = wk[ky*3+2];
        a0 += k0*e0 + k1*e1 + k2*e2;
        a1 += k0*e1 + k1*e2 + k2*e3;
        a2 += k0*e2 + k1*e3 + k2*e4;
        a3 += k0*e3 + k1*e4 + k2*e5;
      }
      dout4[oc4][0] = a0; dout4[oc4][1] = a1;
      dout4[oc4][2] = a2; dout4[oc4][3] = a3;
    }
  };

  for (int n = 0; n < 4; ++n) {
    gemm_chunk(16 * n);                 // q head n
    __syncthreads();
    dw_chunk(16 * n);
    #pragma unroll
    for (int oc4 = 0; oc4 < 4; ++oc4)
      #pragma unroll
      for (int i = 0; i < 4; ++i)
        qc[QC_IDX(wid*4 + oc4, dpy*16 + dg*4 + i)] = f2bf(dout4[oc4][i]);
    __syncthreads();
    {
      int ch = tid >> 4, seg = tid & 15;
      float s = 0.f;
      #pragma unroll
      for (int j = 0; j < 16; ++j) { float v = bf2f(qc[QC_IDX(ch, seg * 16 + j)]); s += v * v; }
      s += __shfl_xor(s, 1); s += __shfl_xor(s, 2); s += __shfl_xor(s, 4); s += __shfl_xor(s, 8);
      if (seg == 0) Nqp[(size_t)blk * 64 + n * 16 + ch] = s;
    }
    gemm_chunk(64 + 16 * n);            // k head n
    __syncthreads();
    dw_chunk(64 + 16 * n);
    #pragma unroll
    for (int oc4 = 0; oc4 < 4; ++oc4)
      #pragma unroll
      for (int i = 0; i < 4; ++i)
        kc[QC_IDX(wid*4 + oc4, dpy*16 + dg*4 + i)] = f2bf(dout4[oc4][i]);
    __syncthreads();
    {
      int ch = tid >> 4, seg = tid & 15;
      float s = 0.f;
      #pragma unroll
      for (int j = 0; j < 16; ++j) { float v = bf2f(kc[QC_IDX(ch, seg * 16 + j)]); s += v * v; }
      s += __shfl_xor(s, 1); s += __shfl_xor(s, 2); s += __shfl_xor(s, 4); s += __shfl_xor(s, 8);
      if (seg == 0) Nkp[(size_t)blk * 64 + n * 16 + ch] = s;
    }
    if (wid == 0) {                     // Gram_n = q_n @ k_n^T (MFMA, K=256)
      f32x4 g = {0.f, 0.f, 0.f, 0.f};
      #pragma unroll
      for (int s = 0; s < 8; ++s) {
        int G = fk + 4 * s;
        short8v aq = *(const short8v*)&qc[QCG_IDX(fcol, G)];
        short8v bk = *(const short8v*)&kc[QCG_IDX(fcol, G)];
        g = __builtin_amdgcn_mfma_f32_16x16x32_bf16(aq, bk, g, 0, 0, 0);
      }
      float* gp = Gp + ((size_t)blk * 4 + n) * 256;
      #pragma unroll
      for (int r = 0; r < 4; ++r) gp[(fk * 4 + r) * 16 + fcol] = g[r];
    }
  }
  // v chunks: dw -> *illu -> vectorized store
  const float* ib = illu + (size_t)b * 64 * HW;
  for (int j = 0; j < 4; ++j) {
    gemm_chunk(128 + 16 * j);
    __syncthreads();
    dw_chunk(128 + 16 * j);
    int gy = ty0 + dpy, gx = tx0 + dg * 4;
    size_t ppos = (size_t)gy * WIDTH + gx;
    #pragma unroll
    for (int oc4 = 0; oc4 < 4; ++oc4) {
      int vc = 16 * j + wid * 4 + oc4;
      float4 iv4 = *(const float4*)&ib[(size_t)vc * HW + ppos];
      unsigned int lo = (unsigned)f2bf(dout4[oc4][0] * iv4.x)
                      | ((unsigned)f2bf(dout4[oc4][1] * iv4.y) << 16);
      unsigned int hi = (unsigned)f2bf(dout4[oc4][2] * iv4.z)
                      | ((unsigned)f2bf(dout4[oc4][3] * iv4.w) << 16);
      uint2 pk; pk.x = lo; pk.y = hi;
      *(uint2*)&vm[((size_t)b * 64 + vc) * HW + ppos] = pk;
    }
    __syncthreads();
  }
}

// ---------------- two-stage reduction -> softmax -> fold w_out into M ----------------
__global__ __launch_bounds__(256) void k_reduce1(
    const float* __restrict__ Gp, const float* __restrict__ Nqp, const float* __restrict__ Nkp,
    float* __restrict__ G2, float* __restrict__ Nq2, float* __restrict__ Nk2)
{
  const int blk = blockIdx.x;
  const int b = blk >> 5, g = blk & 31;
  const int tid = threadIdx.x;
  float ga[4] = {0.f, 0.f, 0.f, 0.f};
  for (int t = 0; t < 8; ++t) {
    const float* src = Gp + ((size_t)(b * 256 + g * 8 + t)) * 1024;
    #pragma unroll
    for (int j = 0; j < 4; ++j) ga[j] += src[tid + j * 256];
  }
  float* dst = G2 + ((size_t)(b * 32 + g)) * 1024;
  #pragma unroll
  for (int j = 0; j < 4; ++j) dst[tid + j * 256] = ga[j];
  if (tid < 128) {
    int ch = tid & 63; bool isq = tid < 64;
    const float* np = isq ? Nqp : Nkp;
    float s = 0.f;
    for (int t = 0; t < 8; ++t) s += np[((size_t)(b * 256 + g * 8 + t)) * 64 + ch];
    (isq ? Nq2 : Nk2)[(size_t)(b * 32 + g) * 64 + ch] = s;
  }
}

__global__ __launch_bounds__(256) void k_reduce2(
    const float* __restrict__ G2, const float* __restrict__ Nq2, const float* __restrict__ Nk2,
    const float* __restrict__ temp, const float* __restrict__ wout, float* __restrict__ M)
{
  __shared__ float Gs[1024];
  __shared__ float As[4][16][17];
  __shared__ float nq[64], nk[64];
  const int b = blockIdx.x;
  const int tid = threadIdx.x;
  float ga[4] = {0.f, 0.f, 0.f, 0.f};
  for (int g = 0; g < 32; ++g) {
    const float* src = G2 + ((size_t)(b * 32 + g)) * 1024;
    #pragma unroll
    for (int j = 0; j < 4; ++j) ga[j] += src[tid + j * 256];
  }
  #pragma unroll
  for (int j = 0; j < 4; ++j) Gs[tid + j * 256] = ga[j];
  if (tid < 128) {
    int ch = tid & 63; bool isq = tid < 64;
    const float* n2 = isq ? Nq2 : Nk2;
    float s = 0.f;
    for (int g = 0; g < 32; ++g) s += n2[(size_t)(b * 32 + g) * 64 + ch];
    float r = fmaxf(sqrtf(s), 1e-12f);
    (isq ? nq : nk)[ch] = r;
  }
  __syncthreads();
  if (tid < 64) {
    int n = tid >> 4, d = tid & 15;
    float tv = temp[n];
    float row[16]; float mx = -1e30f;
    #pragma unroll
    for (int e = 0; e < 16; ++e) {
      float v = Gs[n * 256 + d * 16 + e] / (nq[n * 16 + d] * nk[n * 16 + e]) * tv;
      row[e] = v; mx = fmaxf(mx, v);
    }
    float s = 0.f;
    #pragma unroll
    for (int e = 0; e < 16; ++e) { float ev = __expf(row[e] - mx); row[e] = ev; s += ev; }
    float inv = 1.f / s;
    #pragma unroll
    for (int e = 0; e < 16; ++e) As[n][d][e] = row[e] * inv;
  }
  __syncthreads();
  float* Mb = M + (size_t)b * 4096;
  for (int i = tid; i < 4096; i += 256) {
    int o = i >> 6, cp = i & 63;
    int n = cp >> 4, e = cp & 15;
    float a = 0.f;
    #pragma unroll
    for (int d = 0; d < 16; ++d) a += wout[o * 64 + n * 16 + d] * As[n][d][e];
    Mb[i] = a;
  }
}

// ---------------- apply M to vm; combine with spatial blob; write out ----------------
__global__ __launch_bounds__(256, 3) void k_mdta_out(
    const unsigned short* __restrict__ vm, const float* __restrict__ M,
    const unsigned short* __restrict__ sp, int use_sp,
    float* __restrict__ out)
{
  __shared__ __align__(16) float Ml[4096];
  __shared__ __align__(16) unsigned short spl[64 * 264];
  const int blk = blockIdx.x;
  const int b = blk >> 8;
  const int y = blk & 255;
  const int tid = threadIdx.x;

  const float* Mb = M + (size_t)b * 4096;
  for (int i = tid; i < 4096; i += 256) Ml[i] = Mb[i];
  if (use_sp) {
    int wy = y >> 3, py = y & 7;
    const unsigned short* spb = sp + ((((size_t)b * 1024 + wy * 32) * 8) + py) * 512;
    for (int k = 0; k < 8; ++k) {
      int i3 = k * 256 + tid;
      int o = i3 & 63, wx = i3 >> 6;
      short8v v8 = *(const short8v*)&spb[(size_t)wx * 4096 + o * 8];
      *(short8v*)&spl[o * 264 + wx * 8] = v8;
    }
  }
  __syncthreads();
  float xcol[64];
  const unsigned short* vb = vm + (size_t)b * 64 * HW + y * 256 + tid;
  #pragma unroll
  for (int c = 0; c < 64; ++c) xcol[c] = bf2f(vb[(size_t)c * HW]);
  float* ob = out + (size_t)b * 64 * HW + y * 256 + tid;
  for (int o = 0; o < 64; ++o) {
    const float4* mr = (const float4*)&Ml[o * 64];
    float acc = 0.f;
    #pragma unroll
    for (int g = 0; g < 16; ++g) {
      float4 m4 = mr[g];
      acc += m4.x * xcol[g*4] + m4.y * xcol[g*4+1] + m4.z * xcol[g*4+2] + m4.w * xcol[g*4+3];
    }
    if (use_sp) ob[(size_t)o * HW] = bf2f(spl[o * 264 + tid]) + acc;
    else        ob[(size_t)o * HW] += acc;
  }
}

extern "C" void kernel_launch(void* const* d_in, const int* in_sizes, int n_in,
                              void* d_out, int out_size, void* d_ws, size_t ws_size,
                              hipStream_t stream) {
  const float* x     = (const float*)d_in[0];
  const float* illu  = (const float*)d_in[1];
  const float* ln1w  = (const float*)d_in[2];
  const float* ln2w  = (const float*)d_in[3];
  const float* wqkv  = (const float*)d_in[4];
  const float* bqkv  = (const float*)d_in[5];
  const float* rpb   = (const float*)d_in[6];
  const float* wproj = (const float*)d_in[7];
  const float* bproj = (const float*)d_in[8];
  const float* temp  = (const float*)d_in[9];
  const float* w1    = (const float*)d_in[10];
  const float* wdw   = (const float*)d_in[11];
  const float* wout  = (const float*)d_in[12];
  float* out = (float*)d_out;

  char* ws = (char*)d_ws;
  unsigned short* vm = (unsigned short*)ws;            // 67,108,864 B
  float* Gp  = (float*)(ws + 67108864);                //  8,388,608 B
  float* Nqp = (float*)(ws + 75497472);                //    524,288 B
  float* Nkp = (float*)(ws + 76021760);                //    524,288 B
  float* G2  = (float*)(ws + 76546048);                //  1,048,576 B
  float* Nq2 = (float*)(ws + 77594624);                //     65,536 B
  float* Nk2 = (float*)(ws + 77660160);                //     65,536 B
  float* M   = (float*)(ws + 77725696);                //    131,072 B
  unsigned short* sp = (unsigned short*)(ws + SP_OFF); // 67,108,864 B (if available)
  int use_sp = (ws_size >= SP_OFF + 67108864ull) ? 1 : 0;

  k_spatial<<<8192, 256, 0, stream>>>(x, illu, ln1w, wqkv, bqkv, rpb, wproj, bproj,
                                      out, sp, use_sp);
  k_chan_qkv<<<2048, 256, 0, stream>>>(x, illu, ln2w, w1, wdw, vm, Gp, Nqp, Nkp);
  k_reduce1<<<256, 256, 0, stream>>>(Gp, Nqp, Nkp, G2, Nq2, Nk2);
  k_reduce2<<<8, 256, 0, stream>>>(G2, Nq2, Nk2, temp, wout, M);
  k_mdta_out<<<2048, 256, 0, stream>>>(vm, M, sp, use_sp, out);
}

// Round 9
// 728.042 us; speedup vs baseline: 6.2851x; 1.0840x over previous
//
#include <hip/hip_runtime.h>
#include <hip/hip_bf16.h>

#define HW 65536
#define WIDTH 256
#define SP_OFF 77856768ull   // ws offset of spatial-out blob (67,108,864 B bf16)

typedef __attribute__((ext_vector_type(8))) short short8v;
typedef __attribute__((ext_vector_type(4))) short short4v;
typedef __attribute__((ext_vector_type(4))) float f32x4;

__device__ inline float bf2f(unsigned short u) {
  unsigned int i = ((unsigned int)u) << 16;
  float f; __builtin_memcpy(&f, &i, 4); return f;
}
__device__ inline unsigned short f2bf(float x) {
  __hip_bfloat16 h = __float2bfloat16(x);
  unsigned short u; __builtin_memcpy(&u, &h, 2); return u;
}

// swizzled LDS indexers for k_chan_qkv (granule = 8 bf16 = 16B)
#define XH_IDX(p, g) ((p)*64 + ((((g) ^ ((p)&7)))<<3))
#define QC_IDX(ch, px) ((ch)*256 + ((((px)>>3) ^ ((ch)&7))<<3) + ((px)&7))
#define QCG_IDX(ch, G) ((ch)*256 + ((((G) ^ ((ch)&7)))<<3))

// ---------------- Spatial window-attention branch ----------------
// 2048 WGs, each processes 4 consecutive windows of one batch (b = bid&7 = XCD).
// Weight B-fragments hoisted to registers (no wq LDS) -> 50.7KB LDS, 3 blocks/CU.
__global__ __launch_bounds__(256, 3) void k_spatial(
    const float* __restrict__ x, const float* __restrict__ illu,
    const float* __restrict__ ln1w, const float* __restrict__ wqkv,
    const float* __restrict__ bqkv, const float* __restrict__ rpb,
    const float* __restrict__ wproj, const float* __restrict__ bproj,
    float* __restrict__ out, unsigned short* __restrict__ sp, int use_sp)
{
  __shared__ __align__(16) unsigned short shbuf[9216]; // xw | qs, later 4x P-buffers
  __shared__ __align__(16) unsigned short ks[64*72];   // K -> attn-out
  __shared__ __align__(16) unsigned short vs[64*72];   // V (modulated) -> proj-out
  __shared__ __align__(16) unsigned short vsT[64*72];  // V^T [ch][key], granule-swizzled
  __shared__ float rpbs[900];
  __shared__ float rs_tok[64];

  unsigned short* xw = shbuf;
  unsigned short* qs = shbuf + 4608;

  const int tid = threadIdx.x;
  const int b = blockIdx.x & 7;          // one XCD per batch
  const int grp = blockIdx.x >> 3;       // 0..255 -> windows grp*4 .. grp*4+3
  const float* xb = x + (size_t)b * 64 * HW;
  const float* ib = illu + (size_t)b * 64 * HW;

  const int lane = tid & 63;
  const int w = tid >> 6;
  const int fr = lane & 15;
  const int fg = lane >> 4;
  const int hb = w * 16;

  for (int i = tid; i < 900; i += 256) rpbs[i] = rpb[i];

  // hoist weight B-fragments to registers (loop-invariant; L2/L3-hot)
  short8v bfq[3][2];   // qkv: part, k-half
  float biasr[3];
  #pragma unroll
  for (int part = 0; part < 3; ++part) {
    int o = part * 64 + hb + fr;
    biasr[part] = bqkv[o];
    #pragma unroll
    for (int kh = 0; kh < 2; ++kh)
      #pragma unroll
      for (int j = 0; j < 8; ++j) {
        int c = kh * 32 + fg * 8 + j;
        bfq[part][kh][j] = (short)f2bf(wqkv[c * 192 + o] * ln1w[c]);
      }
  }
  short8v bfp[2];      // proj
  #pragma unroll
  for (int kh = 0; kh < 2; ++kh)
    #pragma unroll
    for (int j = 0; j < 8; ++j) {
      int c = kh * 32 + fg * 8 + j;
      bfp[kh][j] = (short)f2bf(wproj[c * 64 + hb + fr]);
    }

  for (int wi = 0; wi < 4; ++wi) {
    const int win = (grp << 2) + wi;
    const int h0 = (win >> 5) << 3;
    const int w0 = (win & 31) << 3;

    for (int i = tid; i < 1024; i += 256) {
      int c = i >> 4, seg = i & 15;
      int row = seg >> 1, half = (seg & 1) * 4;
      float4 v4 = *(const float4*)&xb[(size_t)c * HW + (h0 + row) * WIDTH + w0 + half];
      int p = row * 8 + half;
      xw[(p+0)*72 + c] = f2bf(v4.x);
      xw[(p+1)*72 + c] = f2bf(v4.y);
      xw[(p+2)*72 + c] = f2bf(v4.z);
      xw[(p+3)*72 + c] = f2bf(v4.w);
    }
    __syncthreads();
    {
      int l = tid >> 2, q4 = tid & 3;
      short8v v8a = *(const short8v*)&xw[l*72 + q4*16];
      short8v v8b = *(const short8v*)&xw[l*72 + q4*16 + 8];
      float s = 0.f, s2 = 0.f;
      #pragma unroll
      for (int j = 0; j < 8; ++j) {
        float va = bf2f((unsigned short)v8a[j]), vb = bf2f((unsigned short)v8b[j]);
        s += va + vb; s2 += va * va + vb * vb;
      }
      s += __shfl_down(s, 1); s2 += __shfl_down(s2, 1);
      s += __shfl_down(s, 2); s2 += __shfl_down(s2, 2);
      if (q4 == 0) {
        float mean = s * 0.015625f;
        float var = s2 * 0.015625f - mean * mean;
        rs_tok[l] = rsqrtf(var + 1e-5f);
      }
    }
    __syncthreads();
    // qkv via MFMA (B-frags in registers)
    {
      short8v a[4][2];
      #pragma unroll
      for (int rt = 0; rt < 4; ++rt)
        #pragma unroll
        for (int kh = 0; kh < 2; ++kh)
          a[rt][kh] = *(const short8v*)&xw[(rt*16 + fr)*72 + kh*32 + fg*8];
      #pragma unroll
      for (int part = 0; part < 3; ++part) {
        float bias = biasr[part];
        #pragma unroll
        for (int rt = 0; rt < 4; ++rt) {
          f32x4 acc = {0.f, 0.f, 0.f, 0.f};
          acc = __builtin_amdgcn_mfma_f32_16x16x32_bf16(a[rt][0], bfq[part][0], acc, 0, 0, 0);
          acc = __builtin_amdgcn_mfma_f32_16x16x32_bf16(a[rt][1], bfq[part][1], acc, 0, 0, 0);
          #pragma unroll
          for (int r = 0; r < 4; ++r) {
            int t = rt*16 + fg*4 + r;
            float val = acc[r] * rs_tok[t] + bias;
            if (part == 0)      qs[t*72 + hb + fr] = f2bf(val * 0.25f);
            else if (part == 1) ks[t*72 + hb + fr] = f2bf(val);
            else                vs[t*72 + hb + fr] = f2bf(val);
          }
        }
      }
    }
    __syncthreads();
    // stage illu -> xw
    for (int i = tid; i < 1024; i += 256) {
      int c = i >> 4, seg = i & 15;
      int row = seg >> 1, half = (seg & 1) * 4;
      float4 v4 = *(const float4*)&ib[(size_t)c * HW + (h0 + row) * WIDTH + w0 + half];
      int p = row * 8 + half;
      xw[(p+0)*72 + c] = f2bf(v4.x);
      xw[(p+1)*72 + c] = f2bf(v4.y);
      xw[(p+2)*72 + c] = f2bf(v4.z);
      xw[(p+3)*72 + c] = f2bf(v4.w);
    }
    __syncthreads();
    // modulate V, build swizzled V^T
    for (int i = tid; i < 4096; i += 256) {
      int l = i >> 6, c = i & 63;
      unsigned short vb16 = f2bf(bf2f(vs[l*72 + c]) * bf2f(xw[l*72 + c]));
      vs[l*72 + c] = vb16;
      vsT[c*72 + ((((l >> 3) ^ (c & 7)) << 3) | (l & 7))] = vb16;
    }
    __syncthreads();
    // attention: S^T = mfma(K,Q), softmax in regs, PV via P-buffers in shbuf
    float inv_s[4];
    {
      short8v zero8 = {0,0,0,0,0,0,0,0};
      short8v kf[4], qf[4];
      #pragma unroll
      for (int t = 0; t < 4; ++t) {
        if (fg < 2) {
          kf[t] = *(const short8v*)&ks[(t*16 + fr)*72 + hb + fg*8];
          qf[t] = *(const short8v*)&qs[(t*16 + fr)*72 + hb + fg*8];
        } else { kf[t] = zero8; qf[t] = zero8; }
      }
      f32x4 st[4][4];
      #pragma unroll
      for (int kt = 0; kt < 4; ++kt)
        #pragma unroll
        for (int qt = 0; qt < 4; ++qt) {
          f32x4 z = {0.f, 0.f, 0.f, 0.f};
          st[kt][qt] = __builtin_amdgcn_mfma_f32_16x16x32_bf16(kf[kt], qf[qt], z, 0, 0, 0);
        }
      float sc[4][16];
      #pragma unroll
      for (int qt = 0; qt < 4; ++qt) {
        int qi = qt*2 + (fr >> 3);
        int qj = fr & 7;
        float mx = -1e30f;
        #pragma unroll
        for (int kt = 0; kt < 4; ++kt) {
          int ki = kt*2 + (fg >> 1);
          int kj0 = (fg & 1) * 4;
          int base = ((qi - ki + 7)*15 + (qj - kj0 + 7))*4 + w;
          #pragma unroll
          for (int r = 0; r < 4; ++r) {
            float v = st[kt][qt][r] + rpbs[base - 4*r];
            sc[qt][kt*4 + r] = v;
            mx = fmaxf(mx, v);
          }
        }
        mx = fmaxf(mx, __shfl_xor(mx, 16));
        mx = fmaxf(mx, __shfl_xor(mx, 32));
        float ss = 0.f;
        #pragma unroll
        for (int j = 0; j < 16; ++j) { float e = __expf(sc[qt][j] - mx); sc[qt][j] = e; ss += e; }
        ss += __shfl_xor(ss, 16);
        ss += __shfl_xor(ss, 32);
        inv_s[qt] = 1.f / ss;
      }
      __syncthreads();
      unsigned short* pb = shbuf + w * 2304;
      f32x4 ot[4];
      #pragma unroll
      for (int nt = 0; nt < 4; ++nt) { f32x4 z = {0.f,0.f,0.f,0.f}; ot[nt] = z; }
      #pragma unroll
      for (int P = 0; P < 2; ++P) {
        #pragma unroll
        for (int qt = 0; qt < 4; ++qt)
          #pragma unroll
          for (int k2 = 0; k2 < 2; ++k2) {
            int kt = 2*P + k2;
            unsigned int lo = (unsigned)f2bf(sc[qt][kt*4+0]) | ((unsigned)f2bf(sc[qt][kt*4+1]) << 16);
            unsigned int hi = (unsigned)f2bf(sc[qt][kt*4+2]) | ((unsigned)f2bf(sc[qt][kt*4+3]) << 16);
            uint2 pk; pk.x = lo; pk.y = hi;
            *(uint2*)&pb[(qt*16 + fr)*36 + k2*16 + fg*4] = pk;
          }
        __syncthreads();
        short8v av = *(const short8v*)&vsT[(hb + fr)*72 + (((P*4 + fg) ^ ((hb + fr) & 7)) << 3)];
        #pragma unroll
        for (int nt = 0; nt < 4; ++nt) {
          short4v p0 = *(const short4v*)&pb[(nt*16 + fr)*36 + fg*8];
          short4v p1 = *(const short4v*)&pb[(nt*16 + fr)*36 + fg*8 + 4];
          short8v bv;
          #pragma unroll
          for (int j = 0; j < 4; ++j) { bv[j] = p0[j]; bv[4+j] = p1[j]; }
          ot[nt] = __builtin_amdgcn_mfma_f32_16x16x32_bf16(av, bv, ot[nt], 0, 0, 0);
        }
        __syncthreads();
      }
      #pragma unroll
      for (int nt = 0; nt < 4; ++nt) {
        float iv = inv_s[nt];
        unsigned int lo = (unsigned)f2bf(ot[nt][0]*iv) | ((unsigned)f2bf(ot[nt][1]*iv) << 16);
        unsigned int hi = (unsigned)f2bf(ot[nt][2]*iv) | ((unsigned)f2bf(ot[nt][3]*iv) << 16);
        uint2 pk; pk.x = lo; pk.y = hi;
        *(uint2*)&ks[(nt*16 + fr)*72 + hb + fg*4] = pk;
      }
    }
    __syncthreads();
    // proj (B-frag in registers); result -> vs
    {
      short8v a[4][2];
      #pragma unroll
      for (int rt = 0; rt < 4; ++rt)
        #pragma unroll
        for (int kh = 0; kh < 2; ++kh)
          a[rt][kh] = *(const short8v*)&ks[(rt*16 + fr)*72 + kh*32 + fg*8];
      #pragma unroll
      for (int rt = 0; rt < 4; ++rt) {
        f32x4 acc = {0.f, 0.f, 0.f, 0.f};
        acc = __builtin_amdgcn_mfma_f32_16x16x32_bf16(a[rt][0], bfp[0], acc, 0, 0, 0);
        acc = __builtin_amdgcn_mfma_f32_16x16x32_bf16(a[rt][1], bfp[1], acc, 0, 0, 0);
        #pragma unroll
        for (int r = 0; r < 4; ++r)
          vs[(rt*16 + fg*4 + r)*72 + hb + fr] = f2bf(acc[r]);
      }
    }
    __syncthreads();
    if (use_sp) {
      unsigned short* spw = sp + (size_t)(b * 1024 + win) * 4096;
      for (int i = tid; i < 1024; i += 256) {
        int row = i >> 7, rem = i & 127;
        int c = rem >> 1, half = (rem & 1) * 4;
        int p = row * 8 + half;
        size_t gofs = (size_t)c * HW + (h0 + row) * WIDTH + w0 + half;
        float4 xr4 = *(const float4*)&xb[gofs];
        float bp = bproj[c];
        unsigned int lo = (unsigned)f2bf(xr4.x + bp + bf2f(vs[(p+0)*72 + c]))
                        | ((unsigned)f2bf(xr4.y + bp + bf2f(vs[(p+1)*72 + c])) << 16);
        unsigned int hi = (unsigned)f2bf(xr4.z + bp + bf2f(vs[(p+2)*72 + c]))
                        | ((unsigned)f2bf(xr4.w + bp + bf2f(vs[(p+3)*72 + c])) << 16);
        uint2 pk; pk.x = lo; pk.y = hi;
        *(uint2*)&spw[row*512 + c*8 + half] = pk;
      }
    } else {
      for (int i = tid; i < 1024; i += 256) {
        int o = i >> 4, seg = i & 15;
        int row = seg >> 1, half = (seg & 1) * 4;
        int p = row * 8 + half;
        size_t gofs = (size_t)o * HW + (h0 + row) * WIDTH + w0 + half;
        float4 xr4 = *(const float4*)&xb[gofs];
        float bp = bproj[o];
        float4 r;
        r.x = xr4.x + bp + bf2f(vs[(p+0)*72 + o]);
        r.y = xr4.y + bp + bf2f(vs[(p+1)*72 + o]);
        r.z = xr4.z + bp + bf2f(vs[(p+2)*72 + o]);
        r.w = xr4.w + bp + bf2f(vs[(p+3)*72 + o]);
        *(float4*)&out[(size_t)b * 64 * HW + gofs] = r;
      }
    }
    __syncthreads();
  }
}

// ---------------- Channel branch: merged 32-channel chunks ----------------
// rsp folded into xh in place (rsp scratch aliased into tb). tb[32][360]
// (20-col rows, 8B-aligned taps). 80.9KB LDS -> 2 blocks/CU, ~14 barriers.
__global__ __launch_bounds__(256, 2) void k_chan_qkv(
    const float* __restrict__ x, const float* __restrict__ illu,
    const float* __restrict__ ln2w, const float* __restrict__ w1,
    const float* __restrict__ wdw,
    unsigned short* __restrict__ vm, float* __restrict__ Gp,
    float* __restrict__ Nqp, float* __restrict__ Nkp)
{
  __shared__ __align__(16) unsigned short xh[324*64];  // x halo * rsp, bf16, swizzled
  __shared__ __align__(16) unsigned short tb[32*360];  // 1x1 out, [oc32][hy*20+hx]
  __shared__ __align__(16) unsigned short qc[16*256];
  __shared__ __align__(16) unsigned short kc[16*256];

  float* rsp = (float*)tb;   // scratch alias, dead before tb's first gemm write

  const int tid = threadIdx.x;
  const int blk = blockIdx.x;
  const int b = blk >> 8;
  const int tile = blk & 255;
  const int ty0 = (tile >> 4) << 4, tx0 = (tile & 15) << 4;
  const float* xb = x + (size_t)b * 64 * HW;

  for (int i = tid; i < 64 * 324; i += 256) {
    int c = i / 324, p = i - c * 324;
    int hy = p / 18, hx = p - hy * 18;
    int gy = ty0 + hy - 1, gx = tx0 + hx - 1;
    float v = 0.f;
    if (gy >= 0 && gy < 256 && gx >= 0 && gx < 256)
      v = xb[(size_t)c * HW + gy * WIDTH + gx];
    xh[XH_IDX(p, c >> 3) + (c & 7)] = f2bf(v);
  }
  __syncthreads();
  for (int p = tid; p < 324; p += 256) {
    float s = 0.f, s2 = 0.f;
    #pragma unroll
    for (int g = 0; g < 8; ++g) {
      short8v v8 = *(const short8v*)&xh[XH_IDX(p, g)];
      #pragma unroll
      for (int j = 0; j < 8; ++j) { float v = bf2f((unsigned short)v8[j]); s += v; s2 += v * v; }
    }
    float mean = s * 0.015625f;
    float var = s2 * 0.015625f - mean * mean;
    rsp[p] = rsqrtf(var + 1e-5f);
  }
  __syncthreads();
  // scale xh in place by rsp (granule of 8 stays within one halo row)
  for (int i = tid; i < 2592; i += 256) {
    int p = i >> 3;
    float rs = rsp[p];
    short8v v8 = *(const short8v*)&xh[i * 8];
    #pragma unroll
    for (int j = 0; j < 8; ++j) v8[j] = (short)f2bf(bf2f((unsigned short)v8[j]) * rs);
    *(short8v*)&xh[i * 8] = v8;
  }
  __syncthreads();

  const int lane = tid & 63;
  const int wid = tid >> 6;
  const int fcol = lane & 15;
  const int fk = lane >> 4;
  const int dpy = (tid >> 2) & 15;
  const int dg = tid & 3;

  // 1x1 conv for 32 output channels (rows qb.. and kb..) in one pass
  auto gemm32 = [&](int qb, int kb) {
    short8v bq[2], bk[2];
    const float* wrq = w1 + (size_t)(qb + fcol) * 64;
    const float* wrk = w1 + (size_t)(kb + fcol) * 64;
    #pragma unroll
    for (int s = 0; s < 2; ++s) {
      int cs = fk * 8 + s * 32;
      #pragma unroll
      for (int j = 0; j < 8; ++j) {
        float lw = ln2w[cs + j];
        bq[s][j] = (short)f2bf(wrq[cs + j] * lw);
        bk[s][j] = (short)f2bf(wrk[cs + j] * lw);
      }
    }
    for (int t = wid; t < 21; t += 4) {
      int ar = t * 16 + fcol;
      short8v a0 = *(const short8v*)&xh[XH_IDX(ar, fk)];      // t=20 rows >=324 read
      short8v a1 = *(const short8v*)&xh[XH_IDX(ar, fk + 4)];  // garbage; outputs discarded
      f32x4 aq = {0.f, 0.f, 0.f, 0.f};
      f32x4 ak = {0.f, 0.f, 0.f, 0.f};
      aq = __builtin_amdgcn_mfma_f32_16x16x32_bf16(a0, bq[0], aq, 0, 0, 0);
      aq = __builtin_amdgcn_mfma_f32_16x16x32_bf16(a1, bq[1], aq, 0, 0, 0);
      ak = __builtin_amdgcn_mfma_f32_16x16x32_bf16(a0, bk[0], ak, 0, 0, 0);
      ak = __builtin_amdgcn_mfma_f32_16x16x32_bf16(a1, bk[1], ak, 0, 0, 0);
      #pragma unroll
      for (int r = 0; r < 4; ++r) {
        int px = t * 16 + fk * 4 + r;
        if (px < 324) {
          int hy = px / 18, hx = px - hy * 18;
          tb[fcol * 360 + hy * 20 + hx]        = f2bf(aq[r]);
          tb[(16 + fcol) * 360 + hy * 20 + hx] = f2bf(ak[r]);
        }
      }
    }
  };

  float dout8[8][4];   // wave handles oc = wid*8 .. +7
  auto dw32 = [&](int qwb, int kwb) {
    #pragma unroll
    for (int oc8 = 0; oc8 < 8; ++oc8) {
      int oc = wid * 8 + oc8;
      int ch = (oc < 16) ? (qwb + oc) : (kwb + oc - 16);
      const float* w9 = wdw + (size_t)ch * 9;
      float wk[9];
      #pragma unroll
      for (int t = 0; t < 9; ++t) wk[t] = w9[t];
      float a0 = 0.f, a1 = 0.f, a2 = 0.f, a3 = 0.f;
      #pragma unroll
      for (int ky = 0; ky < 3; ++ky) {
        int base = oc * 360 + (dpy + ky) * 20 + dg * 4;
        short4v t4 = *(const short4v*)&tb[base];
        unsigned int t2 = *(const unsigned int*)&tb[base + 4];
        float e0 = bf2f((unsigned short)t4[0]);
        float e1 = bf2f((unsigned short)t4[1]);
        float e2 = bf2f((unsigned short)t4[2]);
        float e3 = bf2f((unsigned short)t4[3]);
        float e4 = bf2f((unsigned short)(t2 & 0xffff));
        float e5 = bf2f((unsigned short)(t2 >> 16));
        float k0 = wk[ky*3+0], k1 = wk[ky*3+1], k2 = wk[ky*3+2];
        a0 += k0*e0 + k1*e1 + k2*e2;
        a1 += k0*e1 + k1*e2 + k2*e3;
        a2 += k0*e2 + k1*e3 + k2*e4;
        a3 += k0*e3 + k1*e4 + k2*e5;
      }
      dout8[oc8][0] = a0; dout8[oc8][1] = a1;
      dout8[oc8][2] = a2; dout8[oc8][3] = a3;
    }
  };

  for (int n = 0; n < 4; ++n) {
    gemm32(16 * n, 64 + 16 * n);        // q head n + k head n
    __syncthreads();
    dw32(16 * n, 64 + 16 * n);
    // wid 0,1 -> q rows 0..15 -> qc; wid 2,3 -> k rows 16..31 -> kc
    #pragma unroll
    for (int oc8 = 0; oc8 < 8; ++oc8) {
      int oc = wid * 8 + oc8;
      unsigned short* dst = (oc < 16) ? qc : kc;
      int row = oc & 15;
      #pragma unroll
      for (int i = 0; i < 4; ++i)
        dst[QC_IDX(row, dpy*16 + dg*4 + i)] = f2bf(dout8[oc8][i]);
    }
    __syncthreads();
    {
      int ch = tid >> 4, seg = tid & 15;
      float sq = 0.f, sk = 0.f;
      #pragma unroll
      for (int j = 0; j < 16; ++j) {
        float vq = bf2f(qc[QC_IDX(ch, seg * 16 + j)]); sq += vq * vq;
        float vk = bf2f(kc[QC_IDX(ch, seg * 16 + j)]); sk += vk * vk;
      }
      sq += __shfl_xor(sq, 1); sq += __shfl_xor(sq, 2); sq += __shfl_xor(sq, 4); sq += __shfl_xor(sq, 8);
      sk += __shfl_xor(sk, 1); sk += __shfl_xor(sk, 2); sk += __shfl_xor(sk, 4); sk += __shfl_xor(sk, 8);
      if (seg == 0) {
        Nqp[(size_t)blk * 64 + n * 16 + ch] = sq;
        Nkp[(size_t)blk * 64 + n * 16 + ch] = sk;
      }
    }
    if (wid == 0) {
      f32x4 g = {0.f, 0.f, 0.f, 0.f};
      #pragma unroll
      for (int s = 0; s < 8; ++s) {
        int G = fk + 4 * s;
        short8v aq = *(const short8v*)&qc[QCG_IDX(fcol, G)];
        short8v bk = *(const short8v*)&kc[QCG_IDX(fcol, G)];
        g = __builtin_amdgcn_mfma_f32_16x16x32_bf16(aq, bk, g, 0, 0, 0);
      }
      float* gp = Gp + ((size_t)blk * 4 + n) * 256;
      #pragma unroll
      for (int r = 0; r < 4; ++r) gp[(fk * 4 + r) * 16 + fcol] = g[r];
    }
  }
  // v: 2 merged blocks of 32 channels
  const float* ib = illu + (size_t)b * 64 * HW;
  for (int j = 0; j < 2; ++j) {
    gemm32(128 + 32 * j, 144 + 32 * j);
    __syncthreads();
    dw32(128 + 32 * j, 144 + 32 * j);
    int gy = ty0 + dpy, gx = tx0 + dg * 4;
    size_t ppos = (size_t)gy * WIDTH + gx;
    #pragma unroll
    for (int oc8 = 0; oc8 < 8; ++oc8) {
      int vc = 32 * j + wid * 8 + oc8;
      float4 iv4 = *(const float4*)&ib[(size_t)vc * HW + ppos];
      unsigned int lo = (unsigned)f2bf(dout8[oc8][0] * iv4.x)
                      | ((unsigned)f2bf(dout8[oc8][1] * iv4.y) << 16);
      unsigned int hi = (unsigned)f2bf(dout8[oc8][2] * iv4.z)
                      | ((unsigned)f2bf(dout8[oc8][3] * iv4.w) << 16);
      uint2 pk; pk.x = lo; pk.y = hi;
      *(uint2*)&vm[((size_t)b * 64 + vc) * HW + ppos] = pk;
    }
    __syncthreads();
  }
}

// ---------------- two-stage reduction -> softmax -> fold w_out into M ----------------
__global__ __launch_bounds__(256) void k_reduce1(
    const float* __restrict__ Gp, const float* __restrict__ Nqp, const float* __restrict__ Nkp,
    float* __restrict__ G2, float* __restrict__ Nq2, float* __restrict__ Nk2)
{
  const int blk = blockIdx.x;
  const int b = blk >> 5, g = blk & 31;
  const int tid = threadIdx.x;
  float ga[4] = {0.f, 0.f, 0.f, 0.f};
  for (int t = 0; t < 8; ++t) {
    const float* src = Gp + ((size_t)(b * 256 + g * 8 + t)) * 1024;
    #pragma unroll
    for (int j = 0; j < 4; ++j) ga[j] += src[tid + j * 256];
  }
  float* dst = G2 + ((size_t)(b * 32 + g)) * 1024;
  #pragma unroll
  for (int j = 0; j < 4; ++j) dst[tid + j * 256] = ga[j];
  if (tid < 128) {
    int ch = tid & 63; bool isq = tid < 64;
    const float* np = isq ? Nqp : Nkp;
    float s = 0.f;
    for (int t = 0; t < 8; ++t) s += np[((size_t)(b * 256 + g * 8 + t)) * 64 + ch];
    (isq ? Nq2 : Nk2)[(size_t)(b * 32 + g) * 64 + ch] = s;
  }
}

__global__ __launch_bounds__(256) void k_reduce2(
    const float* __restrict__ G2, const float* __restrict__ Nq2, const float* __restrict__ Nk2,
    const float* __restrict__ temp, const float* __restrict__ wout, float* __restrict__ M)
{
  __shared__ float Gs[1024];
  __shared__ float As[4][16][17];
  __shared__ float nq[64], nk[64];
  const int b = blockIdx.x;
  const int tid = threadIdx.x;
  float ga[4] = {0.f, 0.f, 0.f, 0.f};
  for (int g = 0; g < 32; ++g) {
    const float* src = G2 + ((size_t)(b * 32 + g)) * 1024;
    #pragma unroll
    for (int j = 0; j < 4; ++j) ga[j] += src[tid + j * 256];
  }
  #pragma unroll
  for (int j = 0; j < 4; ++j) Gs[tid + j * 256] = ga[j];
  if (tid < 128) {
    int ch = tid & 63; bool isq = tid < 64;
    const float* n2 = isq ? Nq2 : Nk2;
    float s = 0.f;
    for (int g = 0; g < 32; ++g) s += n2[(size_t)(b * 32 + g) * 64 + ch];
    float r = fmaxf(sqrtf(s), 1e-12f);
    (isq ? nq : nk)[ch] = r;
  }
  __syncthreads();
  if (tid < 64) {
    int n = tid >> 4, d = tid & 15;
    float tv = temp[n];
    float row[16]; float mx = -1e30f;
    #pragma unroll
    for (int e = 0; e < 16; ++e) {
      float v = Gs[n * 256 + d * 16 + e] / (nq[n * 16 + d] * nk[n * 16 + e]) * tv;
      row[e] = v; mx = fmaxf(mx, v);
    }
    float s = 0.f;
    #pragma unroll
    for (int e = 0; e < 16; ++e) { float ev = __expf(row[e] - mx); row[e] = ev; s += ev; }
    float inv = 1.f / s;
    #pragma unroll
    for (int e = 0; e < 16; ++e) As[n][d][e] = row[e] * inv;
  }
  __syncthreads();
  float* Mb = M + (size_t)b * 4096;
  for (int i = tid; i < 4096; i += 256) {
    int o = i >> 6, cp = i & 63;
    int n = cp >> 4, e = cp & 15;
    float a = 0.f;
    #pragma unroll
    for (int d = 0; d < 16; ++d) a += wout[o * 64 + n * 16 + d] * As[n][d][e];
    Mb[i] = a;
  }
}

// ---------------- apply M to vm; combine with spatial blob; write out ----------------
__global__ __launch_bounds__(256, 3) void k_mdta_out(
    const unsigned short* __restrict__ vm, const float* __restrict__ M,
    const unsigned short* __restrict__ sp, int use_sp,
    float* __restrict__ out)
{
  __shared__ __align__(16) float Ml[4096];
  __shared__ __align__(16) unsigned short spl[64 * 264];
  const int blk = blockIdx.x;
  const int b = blk >> 8;
  const int y = blk & 255;
  const int tid = threadIdx.x;

  const float* Mb = M + (size_t)b * 4096;
  for (int i = tid; i < 4096; i += 256) Ml[i] = Mb[i];
  if (use_sp) {
    int wy = y >> 3, py = y & 7;
    const unsigned short* spb = sp + ((((size_t)b * 1024 + wy * 32) * 8) + py) * 512;
    for (int k = 0; k < 8; ++k) {
      int i3 = k * 256 + tid;
      int o = i3 & 63, wx = i3 >> 6;
      short8v v8 = *(const short8v*)&spb[(size_t)wx * 4096 + o * 8];
      *(short8v*)&spl[o * 264 + wx * 8] = v8;
    }
  }
  __syncthreads();
  float xcol[64];
  const unsigned short* vb = vm + (size_t)b * 64 * HW + y * 256 + tid;
  #pragma unroll
  for (int c = 0; c < 64; ++c) xcol[c] = bf2f(vb[(size_t)c * HW]);
  float* ob = out + (size_t)b * 64 * HW + y * 256 + tid;
  for (int o = 0; o < 64; ++o) {
    const float4* mr = (const float4*)&Ml[o * 64];
    float acc = 0.f;
    #pragma unroll
    for (int g = 0; g < 16; ++g) {
      float4 m4 = mr[g];
      acc += m4.x * xcol[g*4] + m4.y * xcol[g*4+1] + m4.z * xcol[g*4+2] + m4.w * xcol[g*4+3];
    }
    if (use_sp) ob[(size_t)o * HW] = bf2f(spl[o * 264 + tid]) + acc;
    else        ob[(size_t)o * HW] += acc;
  }
}

extern "C" void kernel_launch(void* const* d_in, const int* in_sizes, int n_in,
                              void* d_out, int out_size, void* d_ws, size_t ws_size,
                              hipStream_t stream) {
  const float* x     = (const float*)d_in[0];
  const float* illu  = (const float*)d_in[1];
  const float* ln1w  = (const float*)d_in[2];
  const float* ln2w  = (const float*)d_in[3];
  const float* wqkv  = (const float*)d_in[4];
  const float* bqkv  = (const float*)d_in[5];
  const float* rpb   = (const float*)d_in[6];
  const float* wproj = (const float*)d_in[7];
  const float* bproj = (const float*)d_in[8];
  const float* temp  = (const float*)d_in[9];
  const float* w1    = (const float*)d_in[10];
  const float* wdw   = (const float*)d_in[11];
  const float* wout  = (const float*)d_in[12];
  float* out = (float*)d_out;

  char* ws = (char*)d_ws;
  unsigned short* vm = (unsigned short*)ws;            // 67,108,864 B
  float* Gp  = (float*)(ws + 67108864);                //  8,388,608 B
  float* Nqp = (float*)(ws + 75497472);                //    524,288 B
  float* Nkp = (float*)(ws + 76021760);                //    524,288 B
  float* G2  = (float*)(ws + 76546048);                //  1,048,576 B
  float* Nq2 = (float*)(ws + 77594624);                //     65,536 B
  float* Nk2 = (float*)(ws + 77660160);                //     65,536 B
  float* M   = (float*)(ws + 77725696);                //    131,072 B
  unsigned short* sp = (unsigned short*)(ws + SP_OFF); // 67,108,864 B (if available)
  int use_sp = (ws_size >= SP_OFF + 67108864ull) ? 1 : 0;

  k_spatial<<<2048, 256, 0, stream>>>(x, illu, ln1w, wqkv, bqkv, rpb, wproj, bproj,
                                      out, sp, use_sp);
  k_chan_qkv<<<2048, 256, 0, stream>>>(x, illu, ln2w, w1, wdw, vm, Gp, Nqp, Nkp);
  k_reduce1<<<256, 256, 0, stream>>>(Gp, Nqp, Nkp, G2, Nq2, Nk2);
  k_reduce2<<<8, 256, 0, stream>>>(G2, Nq2, Nk2, temp, wout, M);
  k_mdta_out<<<2048, 256, 0, stream>>>(vm, M, sp, use_sp, out);
}